// Round 2
// baseline (2329.716 us; speedup 1.0000x reference)
//
#include <hip/hip_runtime.h>

#define N_NODES 50000
#define N_EDGES 640000
#define D 128
#define D2 256
#define BN_EPS 1e-5f

// ---------------------------------------------------------------------------
// Edge kernel: one wave (64 lanes) per edge; lane owns 2 dims (float2).
// ee = edge_attr @ We[l] + be[l]; msg = relu(h[src]+ee); atomicAdd agg[dst].
// We[l] (8x128) kept in registers (16 floats/lane).
// ---------------------------------------------------------------------------
__global__ __launch_bounds__(256) void edge_kernel(
    const float* __restrict__ h, const int* __restrict__ src,
    const int* __restrict__ dst, const float* __restrict__ ea,
    const float* __restrict__ We_l, const float* __restrict__ be_l,
    float* __restrict__ agg)
{
    const int lane = threadIdx.x & 63;
    const int wave = threadIdx.x >> 6;
    const int d0 = lane * 2;
    float2 wv[8];
#pragma unroll
    for (int k = 0; k < 8; ++k)
        wv[k] = *(const float2*)&We_l[k * D + d0];
    const float2 bev = *(const float2*)&be_l[d0];

    const int e0 = blockIdx.x * 32 + wave * 8;
#pragma unroll 2
    for (int i = 0; i < 8; ++i) {
        const int e = e0 + i;   // grid sized so e < N_EDGES always
        const int s = src[e];
        const int t = dst[e];
        float eav[8];
        *(float4*)&eav[0] = *(const float4*)&ea[(size_t)e * 8];
        *(float4*)&eav[4] = *(const float4*)&ea[(size_t)e * 8 + 4];
        float ex = bev.x, ey = bev.y;
#pragma unroll
        for (int k = 0; k < 8; ++k) {
            ex = fmaf(eav[k], wv[k].x, ex);
            ey = fmaf(eav[k], wv[k].y, ey);
        }
        const float2 hv = *(const float2*)&h[(size_t)s * D + d0];
        const float mx = fmaxf(hv.x + ex, 0.f);
        const float my = fmaxf(hv.y + ey, 0.f);
        float* ap = &agg[(size_t)t * D + d0];
        unsafeAtomicAdd(ap, mx);
        unsafeAtomicAdd(ap + 1, my);
    }
}

// ---------------------------------------------------------------------------
// GEMM1: t1 = ((1+eps)*h + agg) @ W1 + b1   [N,128]@[128,256]
// BM=BN=64, full K=128 staged. Epilogue accumulates per-column sum/sumsq.
// ---------------------------------------------------------------------------
__global__ __launch_bounds__(256) void gemm1_kernel(
    const float* __restrict__ h, const float* __restrict__ agg,
    const float* __restrict__ eps_l, const float* __restrict__ W1_l,
    const float* __restrict__ b1_l, float* __restrict__ t1,
    float* __restrict__ gsum, float* __restrict__ gsq)
{
    __shared__ float As[64][132];   // 132 % 32 == 4 -> <=2-way on f4 reads
    __shared__ float Bs[128][68];
    __shared__ float ls_sum[64];
    __shared__ float ls_sq[64];
    const int tid = threadIdx.x;
    const int M0 = blockIdx.x * 64;
    const int N0 = blockIdx.y * 64;
    const float epsv = 1.0f + eps_l[0];
    if (tid < 64) { ls_sum[tid] = 0.f; ls_sq[tid] = 0.f; }

#pragma unroll
    for (int p = 0; p < 8; ++p) {
        const int idx = p * 256 + tid;
        const int row = idx >> 5;
        const int c4 = (idx & 31) * 4;
        const int grow = M0 + row;
        float4 z = make_float4(0.f, 0.f, 0.f, 0.f);
        if (grow < N_NODES) {
            const float4 hv = *(const float4*)&h[(size_t)grow * D + c4];
            const float4 av = *(const float4*)&agg[(size_t)grow * D + c4];
            z.x = fmaf(epsv, hv.x, av.x);
            z.y = fmaf(epsv, hv.y, av.y);
            z.z = fmaf(epsv, hv.z, av.z);
            z.w = fmaf(epsv, hv.w, av.w);
        }
        *(float4*)&As[row][c4] = z;
    }
#pragma unroll
    for (int p = 0; p < 8; ++p) {
        const int idx = p * 256 + tid;
        const int k = idx >> 4;
        const int n4 = (idx & 15) * 4;
        *(float4*)&Bs[k][n4] = *(const float4*)&W1_l[(size_t)k * D2 + N0 + n4];
    }
    __syncthreads();

    const int tx = tid & 15, ty = tid >> 4;
    const int m0 = ty * 4, n0 = tx * 4;
    float acc[4][4] = {};
#pragma unroll 4
    for (int k4 = 0; k4 < 32; ++k4) {
        float a[4][4];
#pragma unroll
        for (int i = 0; i < 4; ++i)
            *(float4*)&a[i][0] = *(const float4*)&As[m0 + i][k4 * 4];
#pragma unroll
        for (int jj = 0; jj < 4; ++jj) {
            const float4 b = *(const float4*)&Bs[k4 * 4 + jj][n0];
#pragma unroll
            for (int i = 0; i < 4; ++i) {
                acc[i][0] = fmaf(a[i][jj], b.x, acc[i][0]);
                acc[i][1] = fmaf(a[i][jj], b.y, acc[i][1]);
                acc[i][2] = fmaf(a[i][jj], b.z, acc[i][2]);
                acc[i][3] = fmaf(a[i][jj], b.w, acc[i][3]);
            }
        }
    }

    const float4 bias = *(const float4*)&b1_l[N0 + n0];
    float psum[4] = {0,0,0,0}, psq[4] = {0,0,0,0};
#pragma unroll
    for (int i = 0; i < 4; ++i) {
        const int grow = M0 + m0 + i;
        if (grow < N_NODES) {
            float4 v;
            v.x = acc[i][0] + bias.x; v.y = acc[i][1] + bias.y;
            v.z = acc[i][2] + bias.z; v.w = acc[i][3] + bias.w;
            *(float4*)&t1[(size_t)grow * D2 + N0 + n0] = v;
            psum[0] += v.x; psum[1] += v.y; psum[2] += v.z; psum[3] += v.w;
            psq[0] += v.x*v.x; psq[1] += v.y*v.y; psq[2] += v.z*v.z; psq[3] += v.w*v.w;
        }
    }
#pragma unroll
    for (int j = 0; j < 4; ++j) {
        atomicAdd(&ls_sum[n0 + j], psum[j]);
        atomicAdd(&ls_sq[n0 + j], psq[j]);
    }
    __syncthreads();
    if (tid < 64) {
        unsafeAtomicAdd(&gsum[N0 + tid], ls_sum[tid]);
        unsafeAtomicAdd(&gsq[N0 + tid], ls_sq[tid]);
    }
}

// ---------------------------------------------------------------------------
// GEMM2: t2 = relu(bn1(t1)) @ W2 + b2    [N,256]@[256,128]
// BN1 apply fused into A staging (scale/shift precomputed). BK=128, 2 stages.
// ---------------------------------------------------------------------------
__global__ __launch_bounds__(256) void gemm2_kernel(
    const float* __restrict__ t1, const float* __restrict__ scale1,
    const float* __restrict__ shift1, const float* __restrict__ W2_l,
    const float* __restrict__ b2_l, float* __restrict__ t2,
    float* __restrict__ gsum, float* __restrict__ gsq)
{
    __shared__ float As[64][132];
    __shared__ float Bs[128][68];
    __shared__ float ls_sum[64];
    __shared__ float ls_sq[64];
    const int tid = threadIdx.x;
    const int M0 = blockIdx.x * 64;
    const int N0 = blockIdx.y * 64;
    if (tid < 64) { ls_sum[tid] = 0.f; ls_sq[tid] = 0.f; }
    const int tx = tid & 15, ty = tid >> 4;
    const int m0 = ty * 4, n0 = tx * 4;
    float acc[4][4] = {};

    for (int kt = 0; kt < 2; ++kt) {
        if (kt) __syncthreads();
#pragma unroll
        for (int p = 0; p < 8; ++p) {
            const int idx = p * 256 + tid;
            const int row = idx >> 5;
            const int c4 = (idx & 31) * 4;
            const int grow = M0 + row;
            const int col = kt * 128 + c4;
            float4 u = make_float4(0.f, 0.f, 0.f, 0.f);
            if (grow < N_NODES) {
                const float4 tv = *(const float4*)&t1[(size_t)grow * D2 + col];
                const float4 sc = *(const float4*)&scale1[col];
                const float4 sh = *(const float4*)&shift1[col];
                u.x = fmaxf(fmaf(tv.x, sc.x, sh.x), 0.f);
                u.y = fmaxf(fmaf(tv.y, sc.y, sh.y), 0.f);
                u.z = fmaxf(fmaf(tv.z, sc.z, sh.z), 0.f);
                u.w = fmaxf(fmaf(tv.w, sc.w, sh.w), 0.f);
            }
            *(float4*)&As[row][c4] = u;
        }
#pragma unroll
        for (int p = 0; p < 8; ++p) {
            const int idx = p * 256 + tid;
            const int k = idx >> 4;
            const int n4 = (idx & 15) * 4;
            *(float4*)&Bs[k][n4] =
                *(const float4*)&W2_l[(size_t)(kt * 128 + k) * D + N0 + n4];
        }
        __syncthreads();
#pragma unroll 4
        for (int k4 = 0; k4 < 32; ++k4) {
            float a[4][4];
#pragma unroll
            for (int i = 0; i < 4; ++i)
                *(float4*)&a[i][0] = *(const float4*)&As[m0 + i][k4 * 4];
#pragma unroll
            for (int jj = 0; jj < 4; ++jj) {
                const float4 b = *(const float4*)&Bs[k4 * 4 + jj][n0];
#pragma unroll
                for (int i = 0; i < 4; ++i) {
                    acc[i][0] = fmaf(a[i][jj], b.x, acc[i][0]);
                    acc[i][1] = fmaf(a[i][jj], b.y, acc[i][1]);
                    acc[i][2] = fmaf(a[i][jj], b.z, acc[i][2]);
                    acc[i][3] = fmaf(a[i][jj], b.w, acc[i][3]);
                }
            }
        }
    }

    const float4 bias = *(const float4*)&b2_l[N0 + n0];
    float psum[4] = {0,0,0,0}, psq[4] = {0,0,0,0};
#pragma unroll
    for (int i = 0; i < 4; ++i) {
        const int grow = M0 + m0 + i;
        if (grow < N_NODES) {
            float4 v;
            v.x = acc[i][0] + bias.x; v.y = acc[i][1] + bias.y;
            v.z = acc[i][2] + bias.z; v.w = acc[i][3] + bias.w;
            *(float4*)&t2[(size_t)grow * D + N0 + n0] = v;
            psum[0] += v.x; psum[1] += v.y; psum[2] += v.z; psum[3] += v.w;
            psq[0] += v.x*v.x; psq[1] += v.y*v.y; psq[2] += v.z*v.z; psq[3] += v.w*v.w;
        }
    }
#pragma unroll
    for (int j = 0; j < 4; ++j) {
        atomicAdd(&ls_sum[n0 + j], psum[j]);
        atomicAdd(&ls_sq[n0 + j], psq[j]);
    }
    __syncthreads();
    if (tid < 64) {
        unsafeAtomicAdd(&gsum[N0 + tid], ls_sum[tid]);
        unsafeAtomicAdd(&gsq[N0 + tid], ls_sq[tid]);
    }
}

// ---------------------------------------------------------------------------
// BN param: scale = g*rsqrt(var+eps), shift = beta - mu*scale
// ---------------------------------------------------------------------------
__global__ void bnparam_kernel(const float* __restrict__ gsum,
                               const float* __restrict__ gsq,
                               const float* __restrict__ g,
                               const float* __restrict__ bt,
                               float* __restrict__ scale,
                               float* __restrict__ shift, int C)
{
    const int c = threadIdx.x;
    if (c < C) {
        const float inv_n = 1.0f / (float)N_NODES;
        const float mu = gsum[c] * inv_n;
        const float var = gsq[c] * inv_n - mu * mu;
        const float s = g[c] * rsqrtf(var + BN_EPS);
        scale[c] = s;
        shift[c] = bt[c] - mu * s;
    }
}

// ---------------------------------------------------------------------------
// BN apply (+ optional relu), elementwise over [N,128]
// ---------------------------------------------------------------------------
__global__ __launch_bounds__(256) void bn_apply_kernel(
    const float* __restrict__ t2, const float* __restrict__ scale2,
    const float* __restrict__ shift2, float* __restrict__ outp, const int relu)
{
    const size_t idx = (size_t)blockIdx.x * 256 + threadIdx.x;  // float4 index
    const int c = (int)(idx & 31) * 4;
    const float4 v = *(const float4*)&t2[idx * 4];
    const float4 sc = *(const float4*)&scale2[c];
    const float4 sh = *(const float4*)&shift2[c];
    float4 r;
    r.x = fmaf(v.x, sc.x, sh.x);
    r.y = fmaf(v.y, sc.y, sh.y);
    r.z = fmaf(v.z, sc.z, sh.z);
    r.w = fmaf(v.w, sc.w, sh.w);
    if (relu) {
        r.x = fmaxf(r.x, 0.f); r.y = fmaxf(r.y, 0.f);
        r.z = fmaxf(r.z, 0.f); r.w = fmaxf(r.w, 0.f);
    }
    *(float4*)&outp[idx * 4] = r;
}

// ---------------------------------------------------------------------------
extern "C" void kernel_launch(void* const* d_in, const int* in_sizes, int n_in,
                              void* d_out, int out_size, void* d_ws, size_t ws_size,
                              hipStream_t stream)
{
    const float* x         = (const float*)d_in[0];
    const int*   edge_index= (const int*)d_in[1];
    const float* edge_attr = (const float*)d_in[2];
    const float* eps       = (const float*)d_in[3];
    const float* We        = (const float*)d_in[4];
    const float* be        = (const float*)d_in[5];
    const float* W1        = (const float*)d_in[6];
    const float* b1        = (const float*)d_in[7];
    const float* g1        = (const float*)d_in[8];
    const float* bt1       = (const float*)d_in[9];
    const float* W2        = (const float*)d_in[10];
    const float* b2        = (const float*)d_in[11];
    const float* gbn       = (const float*)d_in[12];
    const float* bbn       = (const float*)d_in[13];
    float* out = (float*)d_out;

    float* ws = (float*)d_ws;
    const size_t ND = (size_t)N_NODES * D;       // 6.4M floats
    float* P1   = ws;
    float* P2   = P1 + ND;
    float* AGG  = P2 + ND;
    float* T1   = AGG + ND;                      // N*256
    float* STATS = T1 + (size_t)N_NODES * D2;
    float* gsum1 = STATS;              // 3*256
    float* gsq1  = gsum1 + 3 * 256;
    float* gsum2 = gsq1 + 3 * 256;     // 3*128
    float* gsq2  = gsum2 + 3 * 128;
    float* scale1 = gsq2 + 3 * 128;    // 256
    float* shift1 = scale1 + 256;
    float* scale2 = shift1 + 256;      // 128
    float* shift2 = scale2 + 128;

    const int* srcp = edge_index;
    const int* dstp = edge_index + N_EDGES;

    hipMemsetAsync(STATS, 0, 2304 * sizeof(float), stream);

    const float* h_cur = x;
    float* t2buf[3]  = {P1, P2, P1};
    float* outbuf[3] = {P1, P2, out};

    for (int l = 0; l < 3; ++l) {
        hipMemsetAsync(AGG, 0, ND * sizeof(float), stream);
        edge_kernel<<<N_EDGES / 32, 256, 0, stream>>>(
            h_cur, srcp, dstp, edge_attr,
            We + (size_t)l * 8 * D, be + (size_t)l * D, AGG);

        dim3 grid1((N_NODES + 63) / 64, 4);
        gemm1_kernel<<<grid1, 256, 0, stream>>>(
            h_cur, AGG, eps + l,
            W1 + (size_t)l * D * D2, b1 + (size_t)l * D2, T1,
            gsum1 + l * 256, gsq1 + l * 256);

        bnparam_kernel<<<1, 256, 0, stream>>>(
            gsum1 + l * 256, gsq1 + l * 256,
            g1 + (size_t)l * D2, bt1 + (size_t)l * D2, scale1, shift1, D2);

        dim3 grid2((N_NODES + 63) / 64, 2);
        gemm2_kernel<<<grid2, 256, 0, stream>>>(
            T1, scale1, shift1,
            W2 + (size_t)l * D2 * D, b2 + (size_t)l * D, t2buf[l],
            gsum2 + l * 128, gsq2 + l * 128);

        bnparam_kernel<<<1, 256, 0, stream>>>(
            gsum2 + l * 128, gsq2 + l * 128,
            gbn + (size_t)l * D, bbn + (size_t)l * D, scale2, shift2, D);

        bn_apply_kernel<<<(N_NODES * 32) / 256, 256, 0, stream>>>(
            t2buf[l], scale2, shift2, outbuf[l], l < 2 ? 1 : 0);

        h_cur = outbuf[l];
    }
}

// Round 3
// 1104.877 us; speedup vs baseline: 2.1086x; 2.1086x over previous
//
#include <hip/hip_runtime.h>

#define N_NODES 50000
#define N_EDGES 640000
#define D 128
#define D2 256
#define BN_EPS 1e-5f

// ===========================================================================
// Preprocessing: build CSR permutation of edges by dst (once per call).
//   hist -> exclusive scan (excl) -> scatter (srcp_s[p], eperm[p])
// Persistent arrays live in d_out (unused until final bn_apply overwrites it).
// Transient arrays (hist/scanA/bsum/bscan/cursor) alias into T1 region.
// ===========================================================================

__global__ __launch_bounds__(256) void hist_kernel(
    const int* __restrict__ dst, int* __restrict__ hist)
{
    const int e = blockIdx.x * 256 + threadIdx.x;
    if (e < N_EDGES) atomicAdd(&hist[dst[e]], 1);
}

__global__ __launch_bounds__(256) void scan1_kernel(
    const int* __restrict__ hist, int* __restrict__ scanA,
    int* __restrict__ bsum)
{
    __shared__ int sm[256];
    const int t = threadIdx.x;
    const int idx = blockIdx.x * 256 + t;
    int val = (idx < N_NODES) ? hist[idx] : 0;
    sm[t] = val;
    __syncthreads();
#pragma unroll
    for (int off = 1; off < 256; off <<= 1) {
        const int add = (t >= off) ? sm[t - off] : 0;
        __syncthreads();
        val += add;
        sm[t] = val;
        __syncthreads();
    }
    scanA[idx] = val;
    if (t == 255) bsum[blockIdx.x] = val;
}

__global__ __launch_bounds__(256) void scan2_kernel(
    const int* __restrict__ bsum, int* __restrict__ bscan, int nb)
{
    __shared__ int sm[256];
    const int t = threadIdx.x;
    int val = (t < nb) ? bsum[t] : 0;
    sm[t] = val;
    __syncthreads();
#pragma unroll
    for (int off = 1; off < 256; off <<= 1) {
        const int add = (t >= off) ? sm[t - off] : 0;
        __syncthreads();
        val += add;
        sm[t] = val;
        __syncthreads();
    }
    bscan[t] = val;
}

__global__ __launch_bounds__(256) void scan3_kernel(
    const int* __restrict__ hist, const int* __restrict__ scanA,
    const int* __restrict__ bscan, int* __restrict__ excl)
{
    const int idx = blockIdx.x * 256 + threadIdx.x;
    if (idx < N_NODES) {
        const int carry = blockIdx.x ? bscan[blockIdx.x - 1] : 0;
        const int incl = scanA[idx] + carry;
        excl[idx] = incl - hist[idx];
        if (idx == N_NODES - 1) excl[N_NODES] = incl;   // == N_EDGES
    }
}

__global__ __launch_bounds__(256) void scatter_kernel(
    const int* __restrict__ src, const int* __restrict__ dst,
    int* __restrict__ cursor, int* __restrict__ srcp_s,
    int* __restrict__ eperm)
{
    const int e = blockIdx.x * 256 + threadIdx.x;
    if (e < N_EDGES) {
        const int t = dst[e];
        const int p = atomicAdd(&cursor[t], 1);
        srcp_s[p] = src[e];
        eperm[p] = e;
    }
}

// ===========================================================================
// Aggregation: one wave per node, lane owns 2 dims. Zero atomics.
// agg[n] = sum_{p in [excl[n],excl[n+1])} relu(h[srcp_s[p]] + ea[eperm[p]]@We + be)
// ===========================================================================
__global__ __launch_bounds__(256) void agg_kernel(
    const float* __restrict__ h, const int* __restrict__ excl,
    const int* __restrict__ srcp_s, const int* __restrict__ eperm,
    const float* __restrict__ ea, const float* __restrict__ We_l,
    const float* __restrict__ be_l, float* __restrict__ agg)
{
    const int lane = threadIdx.x & 63;
    const int wave = threadIdx.x >> 6;
    const int node = blockIdx.x * 4 + wave;      // grid sized exactly
    const int d0 = lane * 2;

    float2 wv[8];
#pragma unroll
    for (int k = 0; k < 8; ++k)
        wv[k] = *(const float2*)&We_l[k * D + d0];
    const float2 bev = *(const float2*)&be_l[d0];

    const int p0 = excl[node];
    const int p1 = excl[node + 1];
    float ax = 0.f, ay = 0.f;
    for (int p = p0; p < p1; ++p) {
        const int e = eperm[p];
        const int s = srcp_s[p];
        float eav[8];
        *(float4*)&eav[0] = *(const float4*)&ea[(size_t)e * 8];
        *(float4*)&eav[4] = *(const float4*)&ea[(size_t)e * 8 + 4];
        float ex = bev.x, ey = bev.y;
#pragma unroll
        for (int k = 0; k < 8; ++k) {
            ex = fmaf(eav[k], wv[k].x, ex);
            ey = fmaf(eav[k], wv[k].y, ey);
        }
        const float2 hv = *(const float2*)&h[(size_t)s * D + d0];
        ax += fmaxf(hv.x + ex, 0.f);
        ay += fmaxf(hv.y + ey, 0.f);
    }
    *(float2*)&agg[(size_t)node * D + d0] = make_float2(ax, ay);
}

// ---------------------------------------------------------------------------
// GEMM1: t1 = ((1+eps)*h + agg) @ W1 + b1   [N,128]@[128,256]
// ---------------------------------------------------------------------------
__global__ __launch_bounds__(256) void gemm1_kernel(
    const float* __restrict__ h, const float* __restrict__ agg,
    const float* __restrict__ eps_l, const float* __restrict__ W1_l,
    const float* __restrict__ b1_l, float* __restrict__ t1,
    float* __restrict__ gsum, float* __restrict__ gsq)
{
    __shared__ float As[64][132];
    __shared__ float Bs[128][68];
    __shared__ float ls_sum[64];
    __shared__ float ls_sq[64];
    const int tid = threadIdx.x;
    const int M0 = blockIdx.x * 64;
    const int N0 = blockIdx.y * 64;
    const float epsv = 1.0f + eps_l[0];
    if (tid < 64) { ls_sum[tid] = 0.f; ls_sq[tid] = 0.f; }

#pragma unroll
    for (int p = 0; p < 8; ++p) {
        const int idx = p * 256 + tid;
        const int row = idx >> 5;
        const int c4 = (idx & 31) * 4;
        const int grow = M0 + row;
        float4 z = make_float4(0.f, 0.f, 0.f, 0.f);
        if (grow < N_NODES) {
            const float4 hv = *(const float4*)&h[(size_t)grow * D + c4];
            const float4 av = *(const float4*)&agg[(size_t)grow * D + c4];
            z.x = fmaf(epsv, hv.x, av.x);
            z.y = fmaf(epsv, hv.y, av.y);
            z.z = fmaf(epsv, hv.z, av.z);
            z.w = fmaf(epsv, hv.w, av.w);
        }
        *(float4*)&As[row][c4] = z;
    }
#pragma unroll
    for (int p = 0; p < 8; ++p) {
        const int idx = p * 256 + tid;
        const int k = idx >> 4;
        const int n4 = (idx & 15) * 4;
        *(float4*)&Bs[k][n4] = *(const float4*)&W1_l[(size_t)k * D2 + N0 + n4];
    }
    __syncthreads();

    const int tx = tid & 15, ty = tid >> 4;
    const int m0 = ty * 4, n0 = tx * 4;
    float acc[4][4] = {};
#pragma unroll 4
    for (int k4 = 0; k4 < 32; ++k4) {
        float a[4][4];
#pragma unroll
        for (int i = 0; i < 4; ++i)
            *(float4*)&a[i][0] = *(const float4*)&As[m0 + i][k4 * 4];
#pragma unroll
        for (int jj = 0; jj < 4; ++jj) {
            const float4 b = *(const float4*)&Bs[k4 * 4 + jj][n0];
#pragma unroll
            for (int i = 0; i < 4; ++i) {
                acc[i][0] = fmaf(a[i][jj], b.x, acc[i][0]);
                acc[i][1] = fmaf(a[i][jj], b.y, acc[i][1]);
                acc[i][2] = fmaf(a[i][jj], b.z, acc[i][2]);
                acc[i][3] = fmaf(a[i][jj], b.w, acc[i][3]);
            }
        }
    }

    const float4 bias = *(const float4*)&b1_l[N0 + n0];
    float psum[4] = {0,0,0,0}, psq[4] = {0,0,0,0};
#pragma unroll
    for (int i = 0; i < 4; ++i) {
        const int grow = M0 + m0 + i;
        if (grow < N_NODES) {
            float4 v;
            v.x = acc[i][0] + bias.x; v.y = acc[i][1] + bias.y;
            v.z = acc[i][2] + bias.z; v.w = acc[i][3] + bias.w;
            *(float4*)&t1[(size_t)grow * D2 + N0 + n0] = v;
            psum[0] += v.x; psum[1] += v.y; psum[2] += v.z; psum[3] += v.w;
            psq[0] += v.x*v.x; psq[1] += v.y*v.y; psq[2] += v.z*v.z; psq[3] += v.w*v.w;
        }
    }
#pragma unroll
    for (int j = 0; j < 4; ++j) {
        atomicAdd(&ls_sum[n0 + j], psum[j]);
        atomicAdd(&ls_sq[n0 + j], psq[j]);
    }
    __syncthreads();
    if (tid < 64) {
        unsafeAtomicAdd(&gsum[N0 + tid], ls_sum[tid]);
        unsafeAtomicAdd(&gsq[N0 + tid], ls_sq[tid]);
    }
}

// ---------------------------------------------------------------------------
// GEMM2: t2 = relu(bn1(t1)) @ W2 + b2    [N,256]@[256,128]
// ---------------------------------------------------------------------------
__global__ __launch_bounds__(256) void gemm2_kernel(
    const float* __restrict__ t1, const float* __restrict__ scale1,
    const float* __restrict__ shift1, const float* __restrict__ W2_l,
    const float* __restrict__ b2_l, float* __restrict__ t2,
    float* __restrict__ gsum, float* __restrict__ gsq)
{
    __shared__ float As[64][132];
    __shared__ float Bs[128][68];
    __shared__ float ls_sum[64];
    __shared__ float ls_sq[64];
    const int tid = threadIdx.x;
    const int M0 = blockIdx.x * 64;
    const int N0 = blockIdx.y * 64;
    if (tid < 64) { ls_sum[tid] = 0.f; ls_sq[tid] = 0.f; }
    const int tx = tid & 15, ty = tid >> 4;
    const int m0 = ty * 4, n0 = tx * 4;
    float acc[4][4] = {};

    for (int kt = 0; kt < 2; ++kt) {
        if (kt) __syncthreads();
#pragma unroll
        for (int p = 0; p < 8; ++p) {
            const int idx = p * 256 + tid;
            const int row = idx >> 5;
            const int c4 = (idx & 31) * 4;
            const int grow = M0 + row;
            const int col = kt * 128 + c4;
            float4 u = make_float4(0.f, 0.f, 0.f, 0.f);
            if (grow < N_NODES) {
                const float4 tv = *(const float4*)&t1[(size_t)grow * D2 + col];
                const float4 sc = *(const float4*)&scale1[col];
                const float4 sh = *(const float4*)&shift1[col];
                u.x = fmaxf(fmaf(tv.x, sc.x, sh.x), 0.f);
                u.y = fmaxf(fmaf(tv.y, sc.y, sh.y), 0.f);
                u.z = fmaxf(fmaf(tv.z, sc.z, sh.z), 0.f);
                u.w = fmaxf(fmaf(tv.w, sc.w, sh.w), 0.f);
            }
            *(float4*)&As[row][c4] = u;
        }
#pragma unroll
        for (int p = 0; p < 8; ++p) {
            const int idx = p * 256 + tid;
            const int k = idx >> 4;
            const int n4 = (idx & 15) * 4;
            *(float4*)&Bs[k][n4] =
                *(const float4*)&W2_l[(size_t)(kt * 128 + k) * D + N0 + n4];
        }
        __syncthreads();
#pragma unroll 4
        for (int k4 = 0; k4 < 32; ++k4) {
            float a[4][4];
#pragma unroll
            for (int i = 0; i < 4; ++i)
                *(float4*)&a[i][0] = *(const float4*)&As[m0 + i][k4 * 4];
#pragma unroll
            for (int jj = 0; jj < 4; ++jj) {
                const float4 b = *(const float4*)&Bs[k4 * 4 + jj][n0];
#pragma unroll
                for (int i = 0; i < 4; ++i) {
                    acc[i][0] = fmaf(a[i][jj], b.x, acc[i][0]);
                    acc[i][1] = fmaf(a[i][jj], b.y, acc[i][1]);
                    acc[i][2] = fmaf(a[i][jj], b.z, acc[i][2]);
                    acc[i][3] = fmaf(a[i][jj], b.w, acc[i][3]);
                }
            }
        }
    }

    const float4 bias = *(const float4*)&b2_l[N0 + n0];
    float psum[4] = {0,0,0,0}, psq[4] = {0,0,0,0};
#pragma unroll
    for (int i = 0; i < 4; ++i) {
        const int grow = M0 + m0 + i;
        if (grow < N_NODES) {
            float4 v;
            v.x = acc[i][0] + bias.x; v.y = acc[i][1] + bias.y;
            v.z = acc[i][2] + bias.z; v.w = acc[i][3] + bias.w;
            *(float4*)&t2[(size_t)grow * D + N0 + n0] = v;
            psum[0] += v.x; psum[1] += v.y; psum[2] += v.z; psum[3] += v.w;
            psq[0] += v.x*v.x; psq[1] += v.y*v.y; psq[2] += v.z*v.z; psq[3] += v.w*v.w;
        }
    }
#pragma unroll
    for (int j = 0; j < 4; ++j) {
        atomicAdd(&ls_sum[n0 + j], psum[j]);
        atomicAdd(&ls_sq[n0 + j], psq[j]);
    }
    __syncthreads();
    if (tid < 64) {
        unsafeAtomicAdd(&gsum[N0 + tid], ls_sum[tid]);
        unsafeAtomicAdd(&gsq[N0 + tid], ls_sq[tid]);
    }
}

// ---------------------------------------------------------------------------
__global__ void bnparam_kernel(const float* __restrict__ gsum,
                               const float* __restrict__ gsq,
                               const float* __restrict__ g,
                               const float* __restrict__ bt,
                               float* __restrict__ scale,
                               float* __restrict__ shift, int C)
{
    const int c = threadIdx.x;
    if (c < C) {
        const float inv_n = 1.0f / (float)N_NODES;
        const float mu = gsum[c] * inv_n;
        const float var = gsq[c] * inv_n - mu * mu;
        const float s = g[c] * rsqrtf(var + BN_EPS);
        scale[c] = s;
        shift[c] = bt[c] - mu * s;
    }
}

// ---------------------------------------------------------------------------
__global__ __launch_bounds__(256) void bn_apply_kernel(
    const float* __restrict__ t2, const float* __restrict__ scale2,
    const float* __restrict__ shift2, float* __restrict__ outp, const int relu)
{
    const size_t idx = (size_t)blockIdx.x * 256 + threadIdx.x;  // float4 index
    const int c = (int)(idx & 31) * 4;
    const float4 v = *(const float4*)&t2[idx * 4];
    const float4 sc = *(const float4*)&scale2[c];
    const float4 sh = *(const float4*)&shift2[c];
    float4 r;
    r.x = fmaf(v.x, sc.x, sh.x);
    r.y = fmaf(v.y, sc.y, sh.y);
    r.z = fmaf(v.z, sc.z, sh.z);
    r.w = fmaf(v.w, sc.w, sh.w);
    if (relu) {
        r.x = fmaxf(r.x, 0.f); r.y = fmaxf(r.y, 0.f);
        r.z = fmaxf(r.z, 0.f); r.w = fmaxf(r.w, 0.f);
    }
    *(float4*)&outp[idx * 4] = r;
}

// ---------------------------------------------------------------------------
extern "C" void kernel_launch(void* const* d_in, const int* in_sizes, int n_in,
                              void* d_out, int out_size, void* d_ws, size_t ws_size,
                              hipStream_t stream)
{
    const float* x         = (const float*)d_in[0];
    const int*   edge_index= (const int*)d_in[1];
    const float* edge_attr = (const float*)d_in[2];
    const float* eps       = (const float*)d_in[3];
    const float* We        = (const float*)d_in[4];
    const float* be        = (const float*)d_in[5];
    const float* W1        = (const float*)d_in[6];
    const float* b1        = (const float*)d_in[7];
    const float* g1        = (const float*)d_in[8];
    const float* bt1       = (const float*)d_in[9];
    const float* W2        = (const float*)d_in[10];
    const float* b2        = (const float*)d_in[11];
    const float* gbn       = (const float*)d_in[12];
    const float* bbn       = (const float*)d_in[13];
    float* out = (float*)d_out;

    float* ws = (float*)d_ws;
    const size_t ND = (size_t)N_NODES * D;       // 6.4M floats
    float* P1   = ws;
    float* P2   = P1 + ND;
    float* AGG  = P2 + ND;
    float* T1   = AGG + ND;                      // N*256 floats
    float* STATS = T1 + (size_t)N_NODES * D2;
    float* gsum1 = STATS;              // 3*256
    float* gsq1  = gsum1 + 3 * 256;
    float* gsum2 = gsq1 + 3 * 256;     // 3*128
    float* gsq2  = gsum2 + 3 * 128;
    float* scale1 = gsq2 + 3 * 128;    // 256
    float* shift1 = scale1 + 256;
    float* scale2 = shift1 + 256;      // 128
    float* shift2 = scale2 + 128;

    // Transient sort scratch aliased into T1 (dead before gemm1 writes T1)
    int* hist   = (int*)T1;            // 50000
    int* scanA  = hist + N_NODES;      // 50176
    int* bsum   = scanA + 50176;       // 256
    int* bscan  = bsum + 256;          // 256
    int* cursor = bscan + 256;         // 50000

    // Persistent CSR arrays in d_out (overwritten by final bn_apply at end)
    int* srcp_s = (int*)d_out;         // 640000
    int* eperm  = srcp_s + N_EDGES;    // 640000
    int* excl   = eperm + N_EDGES;     // 50001

    const int* srcp = edge_index;
    const int* dstp = edge_index + N_EDGES;

    hipMemsetAsync(STATS, 0, 2304 * sizeof(float), stream);
    hipMemsetAsync(hist, 0, N_NODES * sizeof(int), stream);

    const int EB = (N_EDGES + 255) / 256;
    const int NB = (N_NODES + 255) / 256;   // 196
    hist_kernel<<<EB, 256, 0, stream>>>(dstp, hist);
    scan1_kernel<<<NB, 256, 0, stream>>>(hist, scanA, bsum);
    scan2_kernel<<<1, 256, 0, stream>>>(bsum, bscan, NB);
    scan3_kernel<<<NB, 256, 0, stream>>>(hist, scanA, bscan, excl);
    hipMemcpyAsync(cursor, excl, N_NODES * sizeof(int),
                   hipMemcpyDeviceToDevice, stream);
    scatter_kernel<<<EB, 256, 0, stream>>>(srcp, dstp, cursor, srcp_s, eperm);

    const float* h_cur = x;
    float* t2buf[3]  = {P1, P2, P1};
    float* outbuf[3] = {P1, P2, out};

    for (int l = 0; l < 3; ++l) {
        agg_kernel<<<N_NODES / 4, 256, 0, stream>>>(
            h_cur, excl, srcp_s, eperm, edge_attr,
            We + (size_t)l * 8 * D, be + (size_t)l * D, AGG);

        dim3 grid1((N_NODES + 63) / 64, 4);
        gemm1_kernel<<<grid1, 256, 0, stream>>>(
            h_cur, AGG, eps + l,
            W1 + (size_t)l * D * D2, b1 + (size_t)l * D2, T1,
            gsum1 + l * 256, gsq1 + l * 256);

        bnparam_kernel<<<1, 256, 0, stream>>>(
            gsum1 + l * 256, gsq1 + l * 256,
            g1 + (size_t)l * D2, bt1 + (size_t)l * D2, scale1, shift1, D2);

        dim3 grid2((N_NODES + 63) / 64, 2);
        gemm2_kernel<<<grid2, 256, 0, stream>>>(
            T1, scale1, shift1,
            W2 + (size_t)l * D2 * D, b2 + (size_t)l * D, t2buf[l],
            gsum2 + l * 128, gsq2 + l * 128);

        bnparam_kernel<<<1, 256, 0, stream>>>(
            gsum2 + l * 128, gsq2 + l * 128,
            gbn + (size_t)l * D, bbn + (size_t)l * D, scale2, shift2, D);

        bn_apply_kernel<<<(N_NODES * 32) / 256, 256, 0, stream>>>(
            t2buf[l], scale2, shift2, outbuf[l], l < 2 ? 1 : 0);

        h_cur = outbuf[l];
    }
}

// Round 4
// 751.461 us; speedup vs baseline: 3.1002x; 1.4703x over previous
//
#include <hip/hip_runtime.h>

#define N_NODES 50000
#define N_EDGES 640000
#define D 128
#define D2 256
#define BN_EPS 1e-5f

typedef unsigned short ushort_t;
typedef unsigned int uint_t;

using bf16x8 = __attribute__((ext_vector_type(8))) short;
using f32x4  = __attribute__((ext_vector_type(4))) float;

__device__ inline ushort_t f2bf(float f) {
    uint_t u = __builtin_bit_cast(uint_t, f);
    u = (u + 0x7fffu + ((u >> 16) & 1u)) >> 16;   // RTNE
    return (ushort_t)u;
}
__device__ inline float bf2f(uint_t bits_lo16) {
    return __builtin_bit_cast(float, bits_lo16 << 16);
}

// ===========================================================================
// Preprocessing: CSR permutation of edges by dst (once per call).
// ===========================================================================
__global__ __launch_bounds__(256) void hist_kernel(
    const int* __restrict__ dst, int* __restrict__ hist)
{
    const int e = blockIdx.x * 256 + threadIdx.x;
    if (e < N_EDGES) atomicAdd(&hist[dst[e]], 1);
}

__global__ __launch_bounds__(256) void scan1_kernel(
    const int* __restrict__ hist, int* __restrict__ scanA,
    int* __restrict__ bsum)
{
    __shared__ int sm[256];
    const int t = threadIdx.x;
    const int idx = blockIdx.x * 256 + t;
    int val = (idx < N_NODES) ? hist[idx] : 0;
    sm[t] = val;
    __syncthreads();
#pragma unroll
    for (int off = 1; off < 256; off <<= 1) {
        const int add = (t >= off) ? sm[t - off] : 0;
        __syncthreads();
        val += add;
        sm[t] = val;
        __syncthreads();
    }
    scanA[idx] = val;
    if (t == 255) bsum[blockIdx.x] = val;
}

__global__ __launch_bounds__(256) void scan2_kernel(
    const int* __restrict__ bsum, int* __restrict__ bscan, int nb)
{
    __shared__ int sm[256];
    const int t = threadIdx.x;
    int val = (t < nb) ? bsum[t] : 0;
    sm[t] = val;
    __syncthreads();
#pragma unroll
    for (int off = 1; off < 256; off <<= 1) {
        const int add = (t >= off) ? sm[t - off] : 0;
        __syncthreads();
        val += add;
        sm[t] = val;
        __syncthreads();
    }
    bscan[t] = val;
}

__global__ __launch_bounds__(256) void scan3_kernel(
    const int* __restrict__ hist, const int* __restrict__ scanA,
    const int* __restrict__ bscan, int* __restrict__ excl)
{
    const int idx = blockIdx.x * 256 + threadIdx.x;
    if (idx < N_NODES) {
        const int carry = blockIdx.x ? bscan[blockIdx.x - 1] : 0;
        const int incl = scanA[idx] + carry;
        excl[idx] = incl - hist[idx];
        if (idx == N_NODES - 1) excl[N_NODES] = incl;
    }
}

__global__ __launch_bounds__(256) void scatter_kernel(
    const int* __restrict__ src, const int* __restrict__ dst,
    int* __restrict__ cursor, int* __restrict__ srcp_s,
    int* __restrict__ eperm)
{
    const int e = blockIdx.x * 256 + threadIdx.x;
    if (e < N_EDGES) {
        const int t = dst[e];
        const int p = atomicAdd(&cursor[t], 1);
        srcp_s[p] = src[e];
        eperm[p] = e;
    }
}

// ===========================================================================
// W transpose + bf16 convert: in fp32 [L][K][Nt] -> out bf16 [L][Nt][K]
// ===========================================================================
__global__ __launch_bounds__(256) void wtrans_kernel(
    const float* __restrict__ in, ushort_t* __restrict__ out, int K, int Nt)
{
    __shared__ float tile[32][33];
    const int l = blockIdx.z;
    in  += (size_t)l * K * Nt;
    out += (size_t)l * K * Nt;
    const int n0 = blockIdx.x * 32, k0 = blockIdx.y * 32;
    const int tx = threadIdx.x & 31, ty = threadIdx.x >> 5;   // 32 x 8
#pragma unroll
    for (int i = 0; i < 32; i += 8)
        tile[ty + i][tx] = in[(size_t)(k0 + ty + i) * Nt + n0 + tx];
    __syncthreads();
#pragma unroll
    for (int i = 0; i < 32; i += 8)
        out[(size_t)(n0 + ty + i) * K + k0 + tx] = f2bf(tile[tx][ty + i]);
}

// ===========================================================================
// Aggregation + z: one wave per node, lane owns 2 dims. Zero atomics.
// z[n] = bf16( (1+eps)*h[n] + sum relu(h[src] + ea@We + be) )
// ===========================================================================
__global__ __launch_bounds__(256) void agg_z_kernel(
    const float* __restrict__ h, const int* __restrict__ excl,
    const int* __restrict__ srcp_s, const int* __restrict__ eperm,
    const float* __restrict__ ea, const float* __restrict__ We_l,
    const float* __restrict__ be_l, const float* __restrict__ eps_l,
    ushort_t* __restrict__ z)
{
    const int lane = threadIdx.x & 63;
    const int wave = threadIdx.x >> 6;
    const int node = blockIdx.x * 4 + wave;
    const int d0 = lane * 2;

    float2 wv[8];
#pragma unroll
    for (int k = 0; k < 8; ++k)
        wv[k] = *(const float2*)&We_l[k * D + d0];
    const float2 bev = *(const float2*)&be_l[d0];

    const int p0 = excl[node];
    const int p1 = excl[node + 1];
    float ax = 0.f, ay = 0.f;
    for (int p = p0; p < p1; ++p) {
        const int e = eperm[p];
        const int s = srcp_s[p];
        float eav[8];
        *(float4*)&eav[0] = *(const float4*)&ea[(size_t)e * 8];
        *(float4*)&eav[4] = *(const float4*)&ea[(size_t)e * 8 + 4];
        float ex = bev.x, ey = bev.y;
#pragma unroll
        for (int k = 0; k < 8; ++k) {
            ex = fmaf(eav[k], wv[k].x, ex);
            ey = fmaf(eav[k], wv[k].y, ey);
        }
        const float2 hv = *(const float2*)&h[(size_t)s * D + d0];
        ax += fmaxf(hv.x + ex, 0.f);
        ay += fmaxf(hv.y + ey, 0.f);
    }
    const float epsv = 1.0f + eps_l[0];
    const float2 hn = *(const float2*)&h[(size_t)node * D + d0];
    const float zx = fmaf(epsv, hn.x, ax);
    const float zy = fmaf(epsv, hn.y, ay);
    const uint_t packed = (uint_t)f2bf(zx) | ((uint_t)f2bf(zy) << 16);
    *(uint_t*)&z[(size_t)node * D + d0] = packed;
}

// ===========================================================================
// bf16 MFMA GEMM: out[M][Ntot] = A[M][K] @ Bt[Ntot][K]^T + bias, bf16 out,
// fp32 col stats (pre-rounding) accumulated to gsum/gsq.
// BM=BN=BK=128, 256 thr = 4 waves (2x2), wave = 64x64 (4x4 frags 16x16x32).
// ===========================================================================
template<int KTILES>
__global__ __launch_bounds__(256) void gemm_bf16_kernel(
    const ushort_t* __restrict__ A, const ushort_t* __restrict__ Bt,
    const float* __restrict__ bias, ushort_t* __restrict__ out,
    float* __restrict__ gsum, float* __restrict__ gsq)
{
    __shared__ ushort_t As[128][136];   // +8 pad: 272B row stride, 2-way max
    __shared__ ushort_t Bs[128][136];
    __shared__ float ls_sum[128], ls_sq[128];
    const int tid = threadIdx.x;
    const int M0 = blockIdx.x * 128;
    const int N0 = blockIdx.y * 128;
    const int Ntot = gridDim.y * 128;
    const int K = KTILES * 128;
    if (tid < 128) { ls_sum[tid] = 0.f; ls_sq[tid] = 0.f; }
    const int lane = tid & 63, w = tid >> 6;
    const int wm = w >> 1, wn = w & 1;
    const int lr = lane & 15;          // m (A) / n (B) within fragment
    const int lk = (lane >> 4) * 8;    // k sub-offset within 32
    f32x4 acc[4][4] = {};              // [mi][ni]

    for (int kt = 0; kt < KTILES; ++kt) {
        if (kt) __syncthreads();
#pragma unroll
        for (int p = 0; p < 8; ++p) {
            const int idx = p * 256 + tid;
            const int row = idx >> 4, ch = (idx & 15) * 8;
            uint4 v = make_uint4(0, 0, 0, 0);
            const int gr = M0 + row;
            if (gr < N_NODES)
                v = *(const uint4*)&A[(size_t)gr * K + kt * 128 + ch];
            *(uint4*)&As[row][ch] = v;
        }
#pragma unroll
        for (int p = 0; p < 8; ++p) {
            const int idx = p * 256 + tid;
            const int row = idx >> 4, ch = (idx & 15) * 8;
            *(uint4*)&Bs[row][ch] =
                *(const uint4*)&Bt[(size_t)(N0 + row) * K + kt * 128 + ch];
        }
        __syncthreads();
#pragma unroll
        for (int ks = 0; ks < 4; ++ks) {
            const int kof = ks * 32 + lk;
            bf16x8 af[4], bfr[4];
#pragma unroll
            for (int mi = 0; mi < 4; ++mi)
                af[mi] = *(const bf16x8*)&As[wm * 64 + mi * 16 + lr][kof];
#pragma unroll
            for (int ni = 0; ni < 4; ++ni)
                bfr[ni] = *(const bf16x8*)&Bs[wn * 64 + ni * 16 + lr][kof];
#pragma unroll
            for (int mi = 0; mi < 4; ++mi)
#pragma unroll
                for (int ni = 0; ni < 4; ++ni)
                    acc[mi][ni] = __builtin_amdgcn_mfma_f32_16x16x32_bf16(
                        af[mi], bfr[ni], acc[mi][ni], 0, 0, 0);
        }
    }
    __syncthreads();

    // Epilogue: bias, bf16 store, per-column stats.
    // C/D layout: col = lane&15, row = (lane>>4)*4 + reg   [m89-verified]
#pragma unroll
    for (int ni = 0; ni < 4; ++ni) {
        const int cl = wn * 64 + ni * 16 + lr;
        const float bv = bias[N0 + cl];
        float ps = 0.f, pq = 0.f;
#pragma unroll
        for (int mi = 0; mi < 4; ++mi) {
            const int rbase = M0 + wm * 64 + mi * 16 + (lane >> 4) * 4;
#pragma unroll
            for (int r = 0; r < 4; ++r) {
                const int row = rbase + r;
                if (row < N_NODES) {
                    const float v = acc[mi][ni][r] + bv;
                    out[(size_t)row * Ntot + N0 + cl] = f2bf(v);
                    ps += v;
                    pq += v * v;
                }
            }
        }
        atomicAdd(&ls_sum[cl], ps);
        atomicAdd(&ls_sq[cl], pq);
    }
    __syncthreads();
    if (tid < 128) {
        unsafeAtomicAdd(&gsum[N0 + tid], ls_sum[tid]);
        unsafeAtomicAdd(&gsq[N0 + tid], ls_sq[tid]);
    }
}

// ---------------------------------------------------------------------------
__global__ void bnparam_kernel(const float* __restrict__ gsum,
                               const float* __restrict__ gsq,
                               const float* __restrict__ g,
                               const float* __restrict__ bt,
                               float* __restrict__ scale,
                               float* __restrict__ shift, int C)
{
    const int c = threadIdx.x;
    if (c < C) {
        const float inv_n = 1.0f / (float)N_NODES;
        const float mu = gsum[c] * inv_n;
        const float var = gsq[c] * inv_n - mu * mu;
        const float s = g[c] * rsqrtf(var + BN_EPS);
        scale[c] = s;
        shift[c] = bt[c] - mu * s;
    }
}

// ---------------------------------------------------------------------------
// BN1 apply + relu: t1 bf16 [N][256] -> u bf16 [N][256]
// ---------------------------------------------------------------------------
__global__ __launch_bounds__(256) void bnapply1_kernel(
    const ushort_t* __restrict__ t, const float* __restrict__ sc,
    const float* __restrict__ sh, ushort_t* __restrict__ u)
{
    const size_t idx = (size_t)blockIdx.x * 256 + threadIdx.x;  // 8-elem idx
    const int c = (int)(idx & 31) * 8;
    const uint4 v = ((const uint4*)t)[idx];
    const float4 s0 = *(const float4*)&sc[c];
    const float4 s1 = *(const float4*)&sc[c + 4];
    const float4 h0 = *(const float4*)&sh[c];
    const float4 h1 = *(const float4*)&sh[c + 4];
    float f[8];
    f[0] = bf2f(v.x & 0xffffu); f[1] = bf2f(v.x >> 16);
    f[2] = bf2f(v.y & 0xffffu); f[3] = bf2f(v.y >> 16);
    f[4] = bf2f(v.z & 0xffffu); f[5] = bf2f(v.z >> 16);
    f[6] = bf2f(v.w & 0xffffu); f[7] = bf2f(v.w >> 16);
    f[0] = fmaxf(fmaf(f[0], s0.x, h0.x), 0.f);
    f[1] = fmaxf(fmaf(f[1], s0.y, h0.y), 0.f);
    f[2] = fmaxf(fmaf(f[2], s0.z, h0.z), 0.f);
    f[3] = fmaxf(fmaf(f[3], s0.w, h0.w), 0.f);
    f[4] = fmaxf(fmaf(f[4], s1.x, h1.x), 0.f);
    f[5] = fmaxf(fmaf(f[5], s1.y, h1.y), 0.f);
    f[6] = fmaxf(fmaf(f[6], s1.z, h1.z), 0.f);
    f[7] = fmaxf(fmaf(f[7], s1.w, h1.w), 0.f);
    uint4 o;
    o.x = (uint_t)f2bf(f[0]) | ((uint_t)f2bf(f[1]) << 16);
    o.y = (uint_t)f2bf(f[2]) | ((uint_t)f2bf(f[3]) << 16);
    o.z = (uint_t)f2bf(f[4]) | ((uint_t)f2bf(f[5]) << 16);
    o.w = (uint_t)f2bf(f[6]) | ((uint_t)f2bf(f[7]) << 16);
    ((uint4*)u)[idx] = o;
}

// ---------------------------------------------------------------------------
// BN2 apply (+ optional relu): t2 bf16 [N][128] -> h fp32 [N][128]
// ---------------------------------------------------------------------------
__global__ __launch_bounds__(256) void bnapply2_kernel(
    const ushort_t* __restrict__ t, const float* __restrict__ sc,
    const float* __restrict__ sh, float* __restrict__ outp, const int relu)
{
    const size_t idx = (size_t)blockIdx.x * 256 + threadIdx.x;  // 8-elem idx
    const int c = (int)(idx & 15) * 8;
    const uint4 v = ((const uint4*)t)[idx];
    const float4 s0 = *(const float4*)&sc[c];
    const float4 s1 = *(const float4*)&sc[c + 4];
    const float4 h0 = *(const float4*)&sh[c];
    const float4 h1 = *(const float4*)&sh[c + 4];
    float4 r0, r1;
    r0.x = fmaf(bf2f(v.x & 0xffffu), s0.x, h0.x);
    r0.y = fmaf(bf2f(v.x >> 16),     s0.y, h0.y);
    r0.z = fmaf(bf2f(v.y & 0xffffu), s0.z, h0.z);
    r0.w = fmaf(bf2f(v.y >> 16),     s0.w, h0.w);
    r1.x = fmaf(bf2f(v.z & 0xffffu), s1.x, h1.x);
    r1.y = fmaf(bf2f(v.z >> 16),     s1.y, h1.y);
    r1.z = fmaf(bf2f(v.w & 0xffffu), s1.z, h1.z);
    r1.w = fmaf(bf2f(v.w >> 16),     s1.w, h1.w);
    if (relu) {
        r0.x = fmaxf(r0.x, 0.f); r0.y = fmaxf(r0.y, 0.f);
        r0.z = fmaxf(r0.z, 0.f); r0.w = fmaxf(r0.w, 0.f);
        r1.x = fmaxf(r1.x, 0.f); r1.y = fmaxf(r1.y, 0.f);
        r1.z = fmaxf(r1.z, 0.f); r1.w = fmaxf(r1.w, 0.f);
    }
    *(float4*)&outp[idx * 8]     = r0;
    *(float4*)&outp[idx * 8 + 4] = r1;
}

// ---------------------------------------------------------------------------
extern "C" void kernel_launch(void* const* d_in, const int* in_sizes, int n_in,
                              void* d_out, int out_size, void* d_ws, size_t ws_size,
                              hipStream_t stream)
{
    const float* x         = (const float*)d_in[0];
    const int*   edge_index= (const int*)d_in[1];
    const float* edge_attr = (const float*)d_in[2];
    const float* eps       = (const float*)d_in[3];
    const float* We        = (const float*)d_in[4];
    const float* be        = (const float*)d_in[5];
    const float* W1        = (const float*)d_in[6];
    const float* b1        = (const float*)d_in[7];
    const float* g1        = (const float*)d_in[8];
    const float* bt1       = (const float*)d_in[9];
    const float* W2        = (const float*)d_in[10];
    const float* b2        = (const float*)d_in[11];
    const float* gbn       = (const float*)d_in[12];
    const float* bbn       = (const float*)d_in[13];
    float* out = (float*)d_out;

    float* ws = (float*)d_ws;
    const size_t ND = (size_t)N_NODES * D;        // 6.4M floats
    float* P1   = ws;                              // h fp32
    float* P2   = P1 + ND;                         // h fp32
    float* ZT2  = P2 + ND;                         // 6.4M floats: z & t2 (bf16)
    float* T1   = ZT2 + ND;                        // 12.8M floats: t1 & u (bf16)
    float* STATS = T1 + (size_t)N_NODES * D2;
    float* gsum1 = STATS;               // 3*256
    float* gsq1  = gsum1 + 3 * 256;
    float* gsum2 = gsq1 + 3 * 256;      // 3*128
    float* gsq2  = gsum2 + 3 * 128;
    float* scale1 = gsq2 + 3 * 128;     // 256
    float* shift1 = scale1 + 256;
    float* scale2 = shift1 + 256;       // 128
    float* shift2 = scale2 + 128;

    ushort_t* zbuf  = (ushort_t*)ZT2;              // [N][128] bf16
    ushort_t* t2buf = zbuf + ND;                   // [N][128] bf16
    ushort_t* t1buf = (ushort_t*)T1;               // [N][256] bf16
    ushort_t* ubuf  = t1buf + (size_t)N_NODES * D2;// [N][256] bf16

    // Transient sort scratch aliased into T1 (dead before gemm1 writes t1buf)
    int* hist   = (int*)T1;
    int* scanA  = hist + N_NODES;
    int* bsum   = scanA + 50176;
    int* bscan  = bsum + 256;
    int* cursor = bscan + 256;

    // Persistent CSR + bf16 weights in d_out (overwritten by final bnapply2)
    int* srcp_s = (int*)d_out;          // 640000
    int* eperm  = srcp_s + N_EDGES;     // 640000
    int* excl   = eperm + N_EDGES;      // 50001
    ushort_t* W1t = (ushort_t*)((int*)d_out + 1330004);  // 16B aligned; [3][256][128]
    ushort_t* W2t = W1t + 3 * D2 * D;                     // [3][128][256]

    const int* srcp = edge_index;
    const int* dstp = edge_index + N_EDGES;

    hipMemsetAsync(STATS, 0, 2304 * sizeof(float), stream);
    hipMemsetAsync(hist, 0, N_NODES * sizeof(int), stream);

    const int EB = (N_EDGES + 255) / 256;
    const int NB = (N_NODES + 255) / 256;
    hist_kernel<<<EB, 256, 0, stream>>>(dstp, hist);
    scan1_kernel<<<NB, 256, 0, stream>>>(hist, scanA, bsum);
    scan2_kernel<<<1, 256, 0, stream>>>(bsum, bscan, NB);
    scan3_kernel<<<NB, 256, 0, stream>>>(hist, scanA, bscan, excl);
    hipMemcpyAsync(cursor, excl, N_NODES * sizeof(int),
                   hipMemcpyDeviceToDevice, stream);
    scatter_kernel<<<EB, 256, 0, stream>>>(srcp, dstp, cursor, srcp_s, eperm);

    // W1 [3][128][256] -> W1t [3][256][128]; W2 [3][256][128] -> W2t [3][128][256]
    wtrans_kernel<<<dim3(8, 4, 3), 256, 0, stream>>>(W1, W1t, D, D2);
    wtrans_kernel<<<dim3(4, 8, 3), 256, 0, stream>>>(W2, W2t, D2, D);

    const float* h_cur = x;
    float* houtbuf[3] = {P1, P2, out};

    for (int l = 0; l < 3; ++l) {
        agg_z_kernel<<<N_NODES / 4, 256, 0, stream>>>(
            h_cur, excl, srcp_s, eperm, edge_attr,
            We + (size_t)l * 8 * D, be + (size_t)l * D, eps + l, zbuf);

        dim3 grid1((N_NODES + 127) / 128, 2);
        gemm_bf16_kernel<1><<<grid1, 256, 0, stream>>>(
            zbuf, W1t + (size_t)l * D2 * D, b1 + (size_t)l * D2,
            t1buf, gsum1 + l * 256, gsq1 + l * 256);

        bnparam_kernel<<<1, 256, 0, stream>>>(
            gsum1 + l * 256, gsq1 + l * 256,
            g1 + (size_t)l * D2, bt1 + (size_t)l * D2, scale1, shift1, D2);

        bnapply1_kernel<<<(N_NODES * D2 / 8) / 256, 256, 0, stream>>>(
            t1buf, scale1, shift1, ubuf);

        dim3 grid2((N_NODES + 127) / 128, 1);
        gemm_bf16_kernel<2><<<grid2, 256, 0, stream>>>(
            ubuf, W2t + (size_t)l * D * D2, b2 + (size_t)l * D,
            t2buf, gsum2 + l * 128, gsq2 + l * 128);

        bnparam_kernel<<<1, 256, 0, stream>>>(
            gsum2 + l * 128, gsq2 + l * 128,
            gbn + (size_t)l * D, bbn + (size_t)l * D, scale2, shift2, D);

        bnapply2_kernel<<<(N_NODES * D / 8) / 256, 256, 0, stream>>>(
            t2buf, scale2, shift2, houtbuf[l], l < 2 ? 1 : 0);

        h_cur = houtbuf[l];
    }
}

// Round 5
// 711.170 us; speedup vs baseline: 3.2759x; 1.0567x over previous
//
#include <hip/hip_runtime.h>

#define N_NODES 50000
#define N_EDGES 640000
#define D 128
#define D2 256
#define BN_EPS 1e-5f

typedef unsigned short ushort_t;
typedef unsigned int uint_t;

using bf16x8 = __attribute__((ext_vector_type(8))) short;
using f32x4  = __attribute__((ext_vector_type(4))) float;

__device__ inline ushort_t f2bf(float f) {
    uint_t u = __builtin_bit_cast(uint_t, f);
    u = (u + 0x7fffu + ((u >> 16) & 1u)) >> 16;   // RTNE
    return (ushort_t)u;
}
__device__ inline float bf2f(uint_t bits_lo16) {
    return __builtin_bit_cast(float, bits_lo16 << 16);
}

// ===========================================================================
// Preprocessing: CSR permutation of edges by dst (once per call).
// ===========================================================================
__global__ __launch_bounds__(256) void hist_kernel(
    const int* __restrict__ dst, int* __restrict__ hist)
{
    const int e = blockIdx.x * 256 + threadIdx.x;
    if (e < N_EDGES) atomicAdd(&hist[dst[e]], 1);
}

__global__ __launch_bounds__(256) void scan1_kernel(
    const int* __restrict__ hist, int* __restrict__ scanA,
    int* __restrict__ bsum)
{
    __shared__ int sm[256];
    const int t = threadIdx.x;
    const int idx = blockIdx.x * 256 + t;
    int val = (idx < N_NODES) ? hist[idx] : 0;
    sm[t] = val;
    __syncthreads();
#pragma unroll
    for (int off = 1; off < 256; off <<= 1) {
        const int add = (t >= off) ? sm[t - off] : 0;
        __syncthreads();
        val += add;
        sm[t] = val;
        __syncthreads();
    }
    scanA[idx] = val;
    if (t == 255) bsum[blockIdx.x] = val;
}

__global__ __launch_bounds__(256) void scan2_kernel(
    const int* __restrict__ bsum, int* __restrict__ bscan, int nb)
{
    __shared__ int sm[256];
    const int t = threadIdx.x;
    int val = (t < nb) ? bsum[t] : 0;
    sm[t] = val;
    __syncthreads();
#pragma unroll
    for (int off = 1; off < 256; off <<= 1) {
        const int add = (t >= off) ? sm[t - off] : 0;
        __syncthreads();
        val += add;
        sm[t] = val;
        __syncthreads();
    }
    bscan[t] = val;
}

__global__ __launch_bounds__(256) void scan3_kernel(
    const int* __restrict__ hist, const int* __restrict__ scanA,
    const int* __restrict__ bscan, int* __restrict__ excl)
{
    const int idx = blockIdx.x * 256 + threadIdx.x;
    if (idx < N_NODES) {
        const int carry = blockIdx.x ? bscan[blockIdx.x - 1] : 0;
        const int incl = scanA[idx] + carry;
        excl[idx] = incl - hist[idx];
        if (idx == N_NODES - 1) excl[N_NODES] = incl;
    }
}

__global__ __launch_bounds__(256) void scatter_kernel(
    const int* __restrict__ src, const int* __restrict__ dst,
    int* __restrict__ cursor, int* __restrict__ srcp_s,
    int* __restrict__ eperm)
{
    const int e = blockIdx.x * 256 + threadIdx.x;
    if (e < N_EDGES) {
        const int t = dst[e];
        const int p = atomicAdd(&cursor[t], 1);
        srcp_s[p] = src[e];
        eperm[p] = e;
    }
}

// ===========================================================================
// W transpose + bf16 convert: in fp32 [L][K][Nt] -> out bf16 [L][Nt][K]
// ===========================================================================
__global__ __launch_bounds__(256) void wtrans_kernel(
    const float* __restrict__ in, ushort_t* __restrict__ out, int K, int Nt)
{
    __shared__ float tile[32][33];
    const int l = blockIdx.z;
    in  += (size_t)l * K * Nt;
    out += (size_t)l * K * Nt;
    const int n0 = blockIdx.x * 32, k0 = blockIdx.y * 32;
    const int tx = threadIdx.x & 31, ty = threadIdx.x >> 5;   // 32 x 8
#pragma unroll
    for (int i = 0; i < 32; i += 8)
        tile[ty + i][tx] = in[(size_t)(k0 + ty + i) * Nt + n0 + tx];
    __syncthreads();
#pragma unroll
    for (int i = 0; i < 32; i += 8)
        out[(size_t)(n0 + ty + i) * K + k0 + tx] = f2bf(tile[tx][ty + i]);
}

// ===========================================================================
// Aggregation + z: one wave per node, 4 groups of 16 lanes, each group owns
// a different edge (4 gather chains in flight); lane owns 8 dims.
// z[n] = bf16( (1+eps)*h[n] + sum relu(h[src] + ea@We + be) )
// ===========================================================================
__global__ __launch_bounds__(256) void agg_z_kernel(
    const float* __restrict__ h, const int* __restrict__ excl,
    const int* __restrict__ srcp_s, const int* __restrict__ eperm,
    const float* __restrict__ ea, const float* __restrict__ We_l,
    const float* __restrict__ be_l, const float* __restrict__ eps_l,
    ushort_t* __restrict__ z)
{
    const int lane = threadIdx.x & 63;
    const int wave = threadIdx.x >> 6;
    const int node = blockIdx.x * 4 + wave;
    const int grp  = lane >> 4;        // 4 groups of 16 lanes
    const int gl   = lane & 15;
    const int d0   = gl * 8;           // 8 dims owned by this lane

    float wv[8][8];                    // We[k][d0+j]
#pragma unroll
    for (int k = 0; k < 8; ++k) {
        *(float4*)&wv[k][0] = *(const float4*)&We_l[k * D + d0];
        *(float4*)&wv[k][4] = *(const float4*)&We_l[k * D + d0 + 4];
    }
    float bev[8];
    *(float4*)&bev[0] = *(const float4*)&be_l[d0];
    *(float4*)&bev[4] = *(const float4*)&be_l[d0 + 4];

    const int p0 = excl[node];
    const int p1 = excl[node + 1];
    float acc[8] = {0.f, 0.f, 0.f, 0.f, 0.f, 0.f, 0.f, 0.f};

    for (int p = p0 + grp; p < p1; p += 4) {
        const int e = eperm[p];
        const int s = srcp_s[p];
        float eav[8];
        *(float4*)&eav[0] = *(const float4*)&ea[(size_t)e * 8];
        *(float4*)&eav[4] = *(const float4*)&ea[(size_t)e * 8 + 4];
        float hv[8];
        *(float4*)&hv[0] = *(const float4*)&h[(size_t)s * D + d0];
        *(float4*)&hv[4] = *(const float4*)&h[(size_t)s * D + d0 + 4];
        float m[8];
#pragma unroll
        for (int j = 0; j < 8; ++j) m[j] = bev[j];
#pragma unroll
        for (int k = 0; k < 8; ++k)
#pragma unroll
            for (int j = 0; j < 8; ++j)
                m[j] = fmaf(eav[k], wv[k][j], m[j]);
#pragma unroll
        for (int j = 0; j < 8; ++j)
            acc[j] += fmaxf(hv[j] + m[j], 0.f);
    }

    // merge the 4 groups: lanes {gl, gl+16, gl+32, gl+48} hold same dims
#pragma unroll
    for (int j = 0; j < 8; ++j) {
        acc[j] += __shfl_xor(acc[j], 16);
        acc[j] += __shfl_xor(acc[j], 32);
    }

    if (grp == 0) {
        const float epsv = 1.0f + eps_l[0];
        float hn[8];
        *(float4*)&hn[0] = *(const float4*)&h[(size_t)node * D + d0];
        *(float4*)&hn[4] = *(const float4*)&h[(size_t)node * D + d0 + 4];
        uint4 o;
        uint_t w0 = (uint_t)f2bf(fmaf(epsv, hn[0], acc[0]));
        uint_t w1 = (uint_t)f2bf(fmaf(epsv, hn[1], acc[1]));
        uint_t w2 = (uint_t)f2bf(fmaf(epsv, hn[2], acc[2]));
        uint_t w3 = (uint_t)f2bf(fmaf(epsv, hn[3], acc[3]));
        uint_t w4 = (uint_t)f2bf(fmaf(epsv, hn[4], acc[4]));
        uint_t w5 = (uint_t)f2bf(fmaf(epsv, hn[5], acc[5]));
        uint_t w6 = (uint_t)f2bf(fmaf(epsv, hn[6], acc[6]));
        uint_t w7 = (uint_t)f2bf(fmaf(epsv, hn[7], acc[7]));
        o.x = w0 | (w1 << 16);
        o.y = w2 | (w3 << 16);
        o.z = w4 | (w5 << 16);
        o.w = w6 | (w7 << 16);
        *(uint4*)&z[(size_t)node * D + d0] = o;
    }
}

// ===========================================================================
// bf16 MFMA GEMM: out[M][Ntot] = A[M][K] @ Bt[Ntot][K]^T + bias, bf16 out,
// fp32 col stats (pre-rounding) accumulated to gsum/gsq.
// BM=BN=BK=128, 256 thr = 4 waves (2x2), wave = 64x64 (4x4 frags 16x16x32).
// ===========================================================================
template<int KTILES>
__global__ __launch_bounds__(256) void gemm_bf16_kernel(
    const ushort_t* __restrict__ A, const ushort_t* __restrict__ Bt,
    const float* __restrict__ bias, ushort_t* __restrict__ out,
    float* __restrict__ gsum, float* __restrict__ gsq)
{
    __shared__ ushort_t As[128][136];   // +8 pad: 272B row stride, 2-way max
    __shared__ ushort_t Bs[128][136];
    __shared__ float ls_sum[128], ls_sq[128];
    const int tid = threadIdx.x;
    const int M0 = blockIdx.x * 128;
    const int N0 = blockIdx.y * 128;
    const int Ntot = gridDim.y * 128;
    const int K = KTILES * 128;
    if (tid < 128) { ls_sum[tid] = 0.f; ls_sq[tid] = 0.f; }
    const int lane = tid & 63, w = tid >> 6;
    const int wm = w >> 1, wn = w & 1;
    const int lr = lane & 15;          // m (A) / n (B) within fragment
    const int lk = (lane >> 4) * 8;    // k sub-offset within 32
    f32x4 acc[4][4] = {};              // [mi][ni]

    for (int kt = 0; kt < KTILES; ++kt) {
        if (kt) __syncthreads();
#pragma unroll
        for (int p = 0; p < 8; ++p) {
            const int idx = p * 256 + tid;
            const int row = idx >> 4, ch = (idx & 15) * 8;
            uint4 v = make_uint4(0, 0, 0, 0);
            const int gr = M0 + row;
            if (gr < N_NODES)
                v = *(const uint4*)&A[(size_t)gr * K + kt * 128 + ch];
            *(uint4*)&As[row][ch] = v;
        }
#pragma unroll
        for (int p = 0; p < 8; ++p) {
            const int idx = p * 256 + tid;
            const int row = idx >> 4, ch = (idx & 15) * 8;
            *(uint4*)&Bs[row][ch] =
                *(const uint4*)&Bt[(size_t)(N0 + row) * K + kt * 128 + ch];
        }
        __syncthreads();
#pragma unroll
        for (int ks = 0; ks < 4; ++ks) {
            const int kof = ks * 32 + lk;
            bf16x8 af[4], bfr[4];
#pragma unroll
            for (int mi = 0; mi < 4; ++mi)
                af[mi] = *(const bf16x8*)&As[wm * 64 + mi * 16 + lr][kof];
#pragma unroll
            for (int ni = 0; ni < 4; ++ni)
                bfr[ni] = *(const bf16x8*)&Bs[wn * 64 + ni * 16 + lr][kof];
#pragma unroll
            for (int mi = 0; mi < 4; ++mi)
#pragma unroll
                for (int ni = 0; ni < 4; ++ni)
                    acc[mi][ni] = __builtin_amdgcn_mfma_f32_16x16x32_bf16(
                        af[mi], bfr[ni], acc[mi][ni], 0, 0, 0);
        }
    }
    __syncthreads();

    // Epilogue: bias, bf16 store, per-column stats.
    // C/D layout: col = lane&15, row = (lane>>4)*4 + reg   [m89-verified]
#pragma unroll
    for (int ni = 0; ni < 4; ++ni) {
        const int cl = wn * 64 + ni * 16 + lr;
        const float bv = bias[N0 + cl];
        float ps = 0.f, pq = 0.f;
#pragma unroll
        for (int mi = 0; mi < 4; ++mi) {
            const int rbase = M0 + wm * 64 + mi * 16 + (lane >> 4) * 4;
#pragma unroll
            for (int r = 0; r < 4; ++r) {
                const int row = rbase + r;
                if (row < N_NODES) {
                    const float v = acc[mi][ni][r] + bv;
                    out[(size_t)row * Ntot + N0 + cl] = f2bf(v);
                    ps += v;
                    pq += v * v;
                }
            }
        }
        atomicAdd(&ls_sum[cl], ps);
        atomicAdd(&ls_sq[cl], pq);
    }
    __syncthreads();
    if (tid < 128) {
        unsafeAtomicAdd(&gsum[N0 + tid], ls_sum[tid]);
        unsafeAtomicAdd(&gsq[N0 + tid], ls_sq[tid]);
    }
}

// ---------------------------------------------------------------------------
__global__ void bnparam_kernel(const float* __restrict__ gsum,
                               const float* __restrict__ gsq,
                               const float* __restrict__ g,
                               const float* __restrict__ bt,
                               float* __restrict__ scale,
                               float* __restrict__ shift, int C)
{
    const int c = threadIdx.x;
    if (c < C) {
        const float inv_n = 1.0f / (float)N_NODES;
        const float mu = gsum[c] * inv_n;
        const float var = gsq[c] * inv_n - mu * mu;
        const float s = g[c] * rsqrtf(var + BN_EPS);
        scale[c] = s;
        shift[c] = bt[c] - mu * s;
    }
}

// ---------------------------------------------------------------------------
// BN1 apply + relu: t1 bf16 [N][256] -> u bf16 [N][256]
// ---------------------------------------------------------------------------
__global__ __launch_bounds__(256) void bnapply1_kernel(
    const ushort_t* __restrict__ t, const float* __restrict__ sc,
    const float* __restrict__ sh, ushort_t* __restrict__ u)
{
    const size_t idx = (size_t)blockIdx.x * 256 + threadIdx.x;  // 8-elem idx
    const int c = (int)(idx & 31) * 8;
    const uint4 v = ((const uint4*)t)[idx];
    const float4 s0 = *(const float4*)&sc[c];
    const float4 s1 = *(const float4*)&sc[c + 4];
    const float4 h0 = *(const float4*)&sh[c];
    const float4 h1 = *(const float4*)&sh[c + 4];
    float f[8];
    f[0] = bf2f(v.x & 0xffffu); f[1] = bf2f(v.x >> 16);
    f[2] = bf2f(v.y & 0xffffu); f[3] = bf2f(v.y >> 16);
    f[4] = bf2f(v.z & 0xffffu); f[5] = bf2f(v.z >> 16);
    f[6] = bf2f(v.w & 0xffffu); f[7] = bf2f(v.w >> 16);
    f[0] = fmaxf(fmaf(f[0], s0.x, h0.x), 0.f);
    f[1] = fmaxf(fmaf(f[1], s0.y, h0.y), 0.f);
    f[2] = fmaxf(fmaf(f[2], s0.z, h0.z), 0.f);
    f[3] = fmaxf(fmaf(f[3], s0.w, h0.w), 0.f);
    f[4] = fmaxf(fmaf(f[4], s1.x, h1.x), 0.f);
    f[5] = fmaxf(fmaf(f[5], s1.y, h1.y), 0.f);
    f[6] = fmaxf(fmaf(f[6], s1.z, h1.z), 0.f);
    f[7] = fmaxf(fmaf(f[7], s1.w, h1.w), 0.f);
    uint4 o;
    o.x = (uint_t)f2bf(f[0]) | ((uint_t)f2bf(f[1]) << 16);
    o.y = (uint_t)f2bf(f[2]) | ((uint_t)f2bf(f[3]) << 16);
    o.z = (uint_t)f2bf(f[4]) | ((uint_t)f2bf(f[5]) << 16);
    o.w = (uint_t)f2bf(f[6]) | ((uint_t)f2bf(f[7]) << 16);
    ((uint4*)u)[idx] = o;
}

// ---------------------------------------------------------------------------
// BN2 apply (+ optional relu): t2 bf16 [N][128] -> h fp32 [N][128]
// ---------------------------------------------------------------------------
__global__ __launch_bounds__(256) void bnapply2_kernel(
    const ushort_t* __restrict__ t, const float* __restrict__ sc,
    const float* __restrict__ sh, float* __restrict__ outp, const int relu)
{
    const size_t idx = (size_t)blockIdx.x * 256 + threadIdx.x;  // 8-elem idx
    const int c = (int)(idx & 15) * 8;
    const uint4 v = ((const uint4*)t)[idx];
    const float4 s0 = *(const float4*)&sc[c];
    const float4 s1 = *(const float4*)&sc[c + 4];
    const float4 h0 = *(const float4*)&sh[c];
    const float4 h1 = *(const float4*)&sh[c + 4];
    float4 r0, r1;
    r0.x = fmaf(bf2f(v.x & 0xffffu), s0.x, h0.x);
    r0.y = fmaf(bf2f(v.x >> 16),     s0.y, h0.y);
    r0.z = fmaf(bf2f(v.y & 0xffffu), s0.z, h0.z);
    r0.w = fmaf(bf2f(v.y >> 16),     s0.w, h0.w);
    r1.x = fmaf(bf2f(v.z & 0xffffu), s1.x, h1.x);
    r1.y = fmaf(bf2f(v.z >> 16),     s1.y, h1.y);
    r1.z = fmaf(bf2f(v.w & 0xffffu), s1.z, h1.z);
    r1.w = fmaf(bf2f(v.w >> 16),     s1.w, h1.w);
    if (relu) {
        r0.x = fmaxf(r0.x, 0.f); r0.y = fmaxf(r0.y, 0.f);
        r0.z = fmaxf(r0.z, 0.f); r0.w = fmaxf(r0.w, 0.f);
        r1.x = fmaxf(r1.x, 0.f); r1.y = fmaxf(r1.y, 0.f);
        r1.z = fmaxf(r1.z, 0.f); r1.w = fmaxf(r1.w, 0.f);
    }
    *(float4*)&outp[idx * 8]     = r0;
    *(float4*)&outp[idx * 8 + 4] = r1;
}

// ---------------------------------------------------------------------------
extern "C" void kernel_launch(void* const* d_in, const int* in_sizes, int n_in,
                              void* d_out, int out_size, void* d_ws, size_t ws_size,
                              hipStream_t stream)
{
    const float* x         = (const float*)d_in[0];
    const int*   edge_index= (const int*)d_in[1];
    const float* edge_attr = (const float*)d_in[2];
    const float* eps       = (const float*)d_in[3];
    const float* We        = (const float*)d_in[4];
    const float* be        = (const float*)d_in[5];
    const float* W1        = (const float*)d_in[6];
    const float* b1        = (const float*)d_in[7];
    const float* g1        = (const float*)d_in[8];
    const float* bt1       = (const float*)d_in[9];
    const float* W2        = (const float*)d_in[10];
    const float* b2        = (const float*)d_in[11];
    const float* gbn       = (const float*)d_in[12];
    const float* bbn       = (const float*)d_in[13];
    float* out = (float*)d_out;

    float* ws = (float*)d_ws;
    const size_t ND = (size_t)N_NODES * D;        // 6.4M floats
    float* P1   = ws;                              // h fp32
    float* P2   = P1 + ND;                         // h fp32
    float* ZT2  = P2 + ND;                         // 6.4M floats: z & t2 (bf16)
    float* T1   = ZT2 + ND;                        // 12.8M floats: t1 & u (bf16)
    float* STATS = T1 + (size_t)N_NODES * D2;
    float* gsum1 = STATS;               // 3*256
    float* gsq1  = gsum1 + 3 * 256;
    float* gsum2 = gsq1 + 3 * 256;      // 3*128
    float* gsq2  = gsum2 + 3 * 128;
    float* scale1 = gsq2 + 3 * 128;     // 256
    float* shift1 = scale1 + 256;
    float* scale2 = shift1 + 256;       // 128
    float* shift2 = scale2 + 128;

    ushort_t* zbuf  = (ushort_t*)ZT2;              // [N][128] bf16
    ushort_t* t2buf = zbuf + ND;                   // [N][128] bf16
    ushort_t* t1buf = (ushort_t*)T1;               // [N][256] bf16
    ushort_t* ubuf  = t1buf + (size_t)N_NODES * D2;// [N][256] bf16

    // Transient sort scratch aliased into T1 (dead before gemm1 writes t1buf)
    int* hist   = (int*)T1;
    int* scanA  = hist + N_NODES;
    int* bsum   = scanA + 50176;
    int* bscan  = bsum + 256;
    int* cursor = bscan + 256;

    // Persistent CSR + bf16 weights in d_out (overwritten by final bnapply2)
    int* srcp_s = (int*)d_out;          // 640000
    int* eperm  = srcp_s + N_EDGES;     // 640000
    int* excl   = eperm + N_EDGES;      // 50001
    ushort_t* W1t = (ushort_t*)((int*)d_out + 1330004);  // 16B aligned; [3][256][128]
    ushort_t* W2t = W1t + 3 * D2 * D;                     // [3][128][256]

    const int* srcp = edge_index;
    const int* dstp = edge_index + N_EDGES;

    hipMemsetAsync(STATS, 0, 2304 * sizeof(float), stream);
    hipMemsetAsync(hist, 0, N_NODES * sizeof(int), stream);

    const int EB = (N_EDGES + 255) / 256;
    const int NB = (N_NODES + 255) / 256;
    hist_kernel<<<EB, 256, 0, stream>>>(dstp, hist);
    scan1_kernel<<<NB, 256, 0, stream>>>(hist, scanA, bsum);
    scan2_kernel<<<1, 256, 0, stream>>>(bsum, bscan, NB);
    scan3_kernel<<<NB, 256, 0, stream>>>(hist, scanA, bscan, excl);
    hipMemcpyAsync(cursor, excl, N_NODES * sizeof(int),
                   hipMemcpyDeviceToDevice, stream);
    scatter_kernel<<<EB, 256, 0, stream>>>(srcp, dstp, cursor, srcp_s, eperm);

    // W1 [3][128][256] -> W1t [3][256][128]; W2 [3][256][128] -> W2t [3][128][256]
    wtrans_kernel<<<dim3(8, 4, 3), 256, 0, stream>>>(W1, W1t, D, D2);
    wtrans_kernel<<<dim3(4, 8, 3), 256, 0, stream>>>(W2, W2t, D2, D);

    const float* h_cur = x;
    float* houtbuf[3] = {P1, P2, out};

    for (int l = 0; l < 3; ++l) {
        agg_z_kernel<<<N_NODES / 4, 256, 0, stream>>>(
            h_cur, excl, srcp_s, eperm, edge_attr,
            We + (size_t)l * 8 * D, be + (size_t)l * D, eps + l, zbuf);

        dim3 grid1((N_NODES + 127) / 128, 2);
        gemm_bf16_kernel<1><<<grid1, 256, 0, stream>>>(
            zbuf, W1t + (size_t)l * D2 * D, b1 + (size_t)l * D2,
            t1buf, gsum1 + l * 256, gsq1 + l * 256);

        bnparam_kernel<<<1, 256, 0, stream>>>(
            gsum1 + l * 256, gsq1 + l * 256,
            g1 + (size_t)l * D2, bt1 + (size_t)l * D2, scale1, shift1, D2);

        bnapply1_kernel<<<(N_NODES * D2 / 8) / 256, 256, 0, stream>>>(
            t1buf, scale1, shift1, ubuf);

        dim3 grid2((N_NODES + 127) / 128, 1);
        gemm_bf16_kernel<2><<<grid2, 256, 0, stream>>>(
            ubuf, W2t + (size_t)l * D * D2, b2 + (size_t)l * D,
            t2buf, gsum2 + l * 128, gsq2 + l * 128);

        bnparam_kernel<<<1, 256, 0, stream>>>(
            gsum2 + l * 128, gsq2 + l * 128,
            gbn + (size_t)l * D, bbn + (size_t)l * D, scale2, shift2, D);

        bnapply2_kernel<<<(N_NODES * D / 8) / 256, 256, 0, stream>>>(
            t2buf, scale2, shift2, houtbuf[l], l < 2 ? 1 : 0);

        h_cur = houtbuf[l];
    }
}

// Round 6
// 675.723 us; speedup vs baseline: 3.4477x; 1.0525x over previous
//
#include <hip/hip_runtime.h>

#define N_NODES 50000
#define N_EDGES 640000
#define D 128
#define D2 256
#define BN_EPS 1e-5f

typedef unsigned short ushort_t;
typedef unsigned int uint_t;

using bf16x8 = __attribute__((ext_vector_type(8))) short;
using f32x4  = __attribute__((ext_vector_type(4))) float;

__device__ inline ushort_t f2bf(float f) {
    uint_t u = __builtin_bit_cast(uint_t, f);
    u = (u + 0x7fffu + ((u >> 16) & 1u)) >> 16;   // RTNE
    return (ushort_t)u;
}
__device__ inline float bf2f(uint_t bits_lo16) {
    return __builtin_bit_cast(float, bits_lo16 << 16);
}

// ===========================================================================
// Preprocessing: CSR permutation of edges by dst (once per call).
// scatter also pre-permutes edge_attr into ea_s (kills eperm indirection).
// ===========================================================================
__global__ __launch_bounds__(256) void hist_kernel(
    const int* __restrict__ dst, int* __restrict__ hist)
{
    const int e = blockIdx.x * 256 + threadIdx.x;
    if (e < N_EDGES) atomicAdd(&hist[dst[e]], 1);
}

__global__ __launch_bounds__(256) void scan1_kernel(
    const int* __restrict__ hist, int* __restrict__ scanA,
    int* __restrict__ bsum)
{
    __shared__ int sm[256];
    const int t = threadIdx.x;
    const int idx = blockIdx.x * 256 + t;
    int val = (idx < N_NODES) ? hist[idx] : 0;
    sm[t] = val;
    __syncthreads();
#pragma unroll
    for (int off = 1; off < 256; off <<= 1) {
        const int add = (t >= off) ? sm[t - off] : 0;
        __syncthreads();
        val += add;
        sm[t] = val;
        __syncthreads();
    }
    scanA[idx] = val;
    if (t == 255) bsum[blockIdx.x] = val;
}

__global__ __launch_bounds__(256) void scan2_kernel(
    const int* __restrict__ bsum, int* __restrict__ bscan, int nb)
{
    __shared__ int sm[256];
    const int t = threadIdx.x;
    int val = (t < nb) ? bsum[t] : 0;
    sm[t] = val;
    __syncthreads();
#pragma unroll
    for (int off = 1; off < 256; off <<= 1) {
        const int add = (t >= off) ? sm[t - off] : 0;
        __syncthreads();
        val += add;
        sm[t] = val;
        __syncthreads();
    }
    bscan[t] = val;
}

__global__ __launch_bounds__(256) void scan3_kernel(
    const int* __restrict__ hist, const int* __restrict__ scanA,
    const int* __restrict__ bscan, int* __restrict__ excl)
{
    const int idx = blockIdx.x * 256 + threadIdx.x;
    if (idx < N_NODES) {
        const int carry = blockIdx.x ? bscan[blockIdx.x - 1] : 0;
        const int incl = scanA[idx] + carry;
        excl[idx] = incl - hist[idx];
        if (idx == N_NODES - 1) excl[N_NODES] = incl;
    }
}

__global__ __launch_bounds__(256) void scatter_kernel(
    const int* __restrict__ src, const int* __restrict__ dst,
    const float* __restrict__ ea, int* __restrict__ cursor,
    int* __restrict__ srcp_s, float* __restrict__ ea_s)
{
    const int e = blockIdx.x * 256 + threadIdx.x;
    if (e < N_EDGES) {
        const int t = dst[e];
        const int p = atomicAdd(&cursor[t], 1);
        srcp_s[p] = src[e];
        *(float4*)&ea_s[(size_t)p * 8]     = *(const float4*)&ea[(size_t)e * 8];
        *(float4*)&ea_s[(size_t)p * 8 + 4] = *(const float4*)&ea[(size_t)e * 8 + 4];
    }
}

// ===========================================================================
// W transpose + bf16 convert: in fp32 [L][K][Nt] -> out bf16 [L][Nt][K]
// ===========================================================================
__global__ __launch_bounds__(256) void wtrans_kernel(
    const float* __restrict__ in, ushort_t* __restrict__ out, int K, int Nt)
{
    __shared__ float tile[32][33];
    const int l = blockIdx.z;
    in  += (size_t)l * K * Nt;
    out += (size_t)l * K * Nt;
    const int n0 = blockIdx.x * 32, k0 = blockIdx.y * 32;
    const int tx = threadIdx.x & 31, ty = threadIdx.x >> 5;   // 32 x 8
#pragma unroll
    for (int i = 0; i < 32; i += 8)
        tile[ty + i][tx] = in[(size_t)(k0 + ty + i) * Nt + n0 + tx];
    __syncthreads();
#pragma unroll
    for (int i = 0; i < 32; i += 8)
        out[(size_t)(n0 + ty + i) * K + k0 + tx] = f2bf(tile[tx][ty + i]);
}

// ===========================================================================
// Aggregation. One wave per node; 4 groups of 16 lanes each own a different
// edge; lane owns 8 dims; 2-deep pipeline (8 gather chains in flight).
// ===========================================================================
__device__ __forceinline__ void msg_accum(
    const float* __restrict__ hv, const float* __restrict__ eav,
    const float (&wv)[8][8], const float* __restrict__ bev,
    float* __restrict__ acc)
{
    float m[8];
#pragma unroll
    for (int j = 0; j < 8; ++j) m[j] = bev[j];
#pragma unroll
    for (int k = 0; k < 8; ++k)
#pragma unroll
        for (int j = 0; j < 8; ++j)
            m[j] = fmaf(eav[k], wv[k][j], m[j]);
#pragma unroll
    for (int j = 0; j < 8; ++j)
        acc[j] += fmaxf(hv[j] + m[j], 0.f);
}

__device__ __forceinline__ void unpack_bn_relu(
    const uint4 v, const float* __restrict__ scv,
    const float* __restrict__ shv, float* __restrict__ hv)
{
    float f[8];
    f[0] = bf2f(v.x & 0xffffu); f[1] = bf2f(v.x >> 16);
    f[2] = bf2f(v.y & 0xffffu); f[3] = bf2f(v.y >> 16);
    f[4] = bf2f(v.z & 0xffffu); f[5] = bf2f(v.z >> 16);
    f[6] = bf2f(v.w & 0xffffu); f[7] = bf2f(v.w >> 16);
#pragma unroll
    for (int j = 0; j < 8; ++j)
        hv[j] = fmaxf(fmaf(f[j], scv[j], shv[j]), 0.f);
}

__device__ __forceinline__ void store_z(
    ushort_t* __restrict__ z, int node, int d0, float epsv,
    const float* __restrict__ hn, const float* __restrict__ acc)
{
    uint_t w[8];
#pragma unroll
    for (int j = 0; j < 8; ++j)
        w[j] = (uint_t)f2bf(fmaf(epsv, hn[j], acc[j]));
    uint4 o;
    o.x = w[0] | (w[1] << 16);
    o.y = w[2] | (w[3] << 16);
    o.z = w[4] | (w[5] << 16);
    o.w = w[6] | (w[7] << 16);
    *(uint4*)&z[(size_t)node * D + d0] = o;
}

// Layer 0: gather fp32 x rows.
__global__ __launch_bounds__(256) void agg_z_f32_kernel(
    const float* __restrict__ h, const int* __restrict__ excl,
    const int* __restrict__ srcp_s, const float* __restrict__ ea_s,
    const float* __restrict__ We_l, const float* __restrict__ be_l,
    const float* __restrict__ eps_l, ushort_t* __restrict__ z)
{
    const int lane = threadIdx.x & 63;
    const int wave = threadIdx.x >> 6;
    const int node = blockIdx.x * 4 + wave;
    const int grp  = lane >> 4;
    const int gl   = lane & 15;
    const int d0   = gl * 8;

    float wv[8][8];
#pragma unroll
    for (int k = 0; k < 8; ++k) {
        *(float4*)&wv[k][0] = *(const float4*)&We_l[k * D + d0];
        *(float4*)&wv[k][4] = *(const float4*)&We_l[k * D + d0 + 4];
    }
    float bev[8];
    *(float4*)&bev[0] = *(const float4*)&be_l[d0];
    *(float4*)&bev[4] = *(const float4*)&be_l[d0 + 4];

    const int p0 = excl[node];
    const int p1 = excl[node + 1];
    float acc[8] = {0.f, 0.f, 0.f, 0.f, 0.f, 0.f, 0.f, 0.f};

    int p = p0 + grp;
    for (; p + 4 < p1; p += 8) {
        const int sA = srcp_s[p];
        const int sB = srcp_s[p + 4];
        float eA[8], eB[8], hA[8], hB[8];
        *(float4*)&eA[0] = *(const float4*)&ea_s[(size_t)p * 8];
        *(float4*)&eA[4] = *(const float4*)&ea_s[(size_t)p * 8 + 4];
        *(float4*)&eB[0] = *(const float4*)&ea_s[(size_t)(p + 4) * 8];
        *(float4*)&eB[4] = *(const float4*)&ea_s[(size_t)(p + 4) * 8 + 4];
        *(float4*)&hA[0] = *(const float4*)&h[(size_t)sA * D + d0];
        *(float4*)&hA[4] = *(const float4*)&h[(size_t)sA * D + d0 + 4];
        *(float4*)&hB[0] = *(const float4*)&h[(size_t)sB * D + d0];
        *(float4*)&hB[4] = *(const float4*)&h[(size_t)sB * D + d0 + 4];
        msg_accum(hA, eA, wv, bev, acc);
        msg_accum(hB, eB, wv, bev, acc);
    }
    if (p < p1) {
        const int sA = srcp_s[p];
        float eA[8], hA[8];
        *(float4*)&eA[0] = *(const float4*)&ea_s[(size_t)p * 8];
        *(float4*)&eA[4] = *(const float4*)&ea_s[(size_t)p * 8 + 4];
        *(float4*)&hA[0] = *(const float4*)&h[(size_t)sA * D + d0];
        *(float4*)&hA[4] = *(const float4*)&h[(size_t)sA * D + d0 + 4];
        msg_accum(hA, eA, wv, bev, acc);
    }

#pragma unroll
    for (int j = 0; j < 8; ++j) {
        acc[j] += __shfl_xor(acc[j], 16);
        acc[j] += __shfl_xor(acc[j], 32);
    }

    if (grp == 0) {
        float hn[8];
        *(float4*)&hn[0] = *(const float4*)&h[(size_t)node * D + d0];
        *(float4*)&hn[4] = *(const float4*)&h[(size_t)node * D + d0 + 4];
        store_z(z, node, d0, 1.0f + eps_l[0], hn, acc);
    }
}

// Layers 1,2: gather bf16 t2 rows, apply BN2+relu inline (bit-identical to
// materializing h = relu(fmaf(bf2f(t2),sc,sh)) then gathering).
__global__ __launch_bounds__(256) void agg_z_bf16_kernel(
    const ushort_t* __restrict__ t2, const float* __restrict__ sc2,
    const float* __restrict__ sh2, const int* __restrict__ excl,
    const int* __restrict__ srcp_s, const float* __restrict__ ea_s,
    const float* __restrict__ We_l, const float* __restrict__ be_l,
    const float* __restrict__ eps_l, ushort_t* __restrict__ z)
{
    const int lane = threadIdx.x & 63;
    const int wave = threadIdx.x >> 6;
    const int node = blockIdx.x * 4 + wave;
    const int grp  = lane >> 4;
    const int gl   = lane & 15;
    const int d0   = gl * 8;

    float wv[8][8];
#pragma unroll
    for (int k = 0; k < 8; ++k) {
        *(float4*)&wv[k][0] = *(const float4*)&We_l[k * D + d0];
        *(float4*)&wv[k][4] = *(const float4*)&We_l[k * D + d0 + 4];
    }
    float bev[8], scv[8], shv[8];
    *(float4*)&bev[0] = *(const float4*)&be_l[d0];
    *(float4*)&bev[4] = *(const float4*)&be_l[d0 + 4];
    *(float4*)&scv[0] = *(const float4*)&sc2[d0];
    *(float4*)&scv[4] = *(const float4*)&sc2[d0 + 4];
    *(float4*)&shv[0] = *(const float4*)&sh2[d0];
    *(float4*)&shv[4] = *(const float4*)&sh2[d0 + 4];

    const int p0 = excl[node];
    const int p1 = excl[node + 1];
    float acc[8] = {0.f, 0.f, 0.f, 0.f, 0.f, 0.f, 0.f, 0.f};

    int p = p0 + grp;
    for (; p + 4 < p1; p += 8) {
        const int sA = srcp_s[p];
        const int sB = srcp_s[p + 4];
        float eA[8], eB[8];
        *(float4*)&eA[0] = *(const float4*)&ea_s[(size_t)p * 8];
        *(float4*)&eA[4] = *(const float4*)&ea_s[(size_t)p * 8 + 4];
        *(float4*)&eB[0] = *(const float4*)&ea_s[(size_t)(p + 4) * 8];
        *(float4*)&eB[4] = *(const float4*)&ea_s[(size_t)(p + 4) * 8 + 4];
        const uint4 vA = *(const uint4*)&t2[(size_t)sA * D + d0];
        const uint4 vB = *(const uint4*)&t2[(size_t)sB * D + d0];
        float hA[8], hB[8];
        unpack_bn_relu(vA, scv, shv, hA);
        msg_accum(hA, eA, wv, bev, acc);
        unpack_bn_relu(vB, scv, shv, hB);
        msg_accum(hB, eB, wv, bev, acc);
    }
    if (p < p1) {
        const int sA = srcp_s[p];
        float eA[8], hA[8];
        *(float4*)&eA[0] = *(const float4*)&ea_s[(size_t)p * 8];
        *(float4*)&eA[4] = *(const float4*)&ea_s[(size_t)p * 8 + 4];
        const uint4 vA = *(const uint4*)&t2[(size_t)sA * D + d0];
        unpack_bn_relu(vA, scv, shv, hA);
        msg_accum(hA, eA, wv, bev, acc);
    }

#pragma unroll
    for (int j = 0; j < 8; ++j) {
        acc[j] += __shfl_xor(acc[j], 16);
        acc[j] += __shfl_xor(acc[j], 32);
    }

    if (grp == 0) {
        const uint4 vN = *(const uint4*)&t2[(size_t)node * D + d0];
        float hn[8];
        unpack_bn_relu(vN, scv, shv, hn);
        store_z(z, node, d0, 1.0f + eps_l[0], hn, acc);
    }
}

// ===========================================================================
// bf16 MFMA GEMM1: t1 = z @ W1t^T + b1. BM=BN=BK=128, 4 waves (2x2).
// fp32 col stats accumulated to gsum/gsq.
// ===========================================================================
template<int KTILES>
__global__ __launch_bounds__(256) void gemm_bf16_kernel(
    const ushort_t* __restrict__ A, const ushort_t* __restrict__ Bt,
    const float* __restrict__ bias, ushort_t* __restrict__ out,
    float* __restrict__ gsum, float* __restrict__ gsq)
{
    __shared__ ushort_t As[128][136];
    __shared__ ushort_t Bs[128][136];
    __shared__ float ls_sum[128], ls_sq[128];
    const int tid = threadIdx.x;
    const int M0 = blockIdx.x * 128;
    const int N0 = blockIdx.y * 128;
    const int Ntot = gridDim.y * 128;
    const int K = KTILES * 128;
    if (tid < 128) { ls_sum[tid] = 0.f; ls_sq[tid] = 0.f; }
    const int lane = tid & 63, w = tid >> 6;
    const int wm = w >> 1, wn = w & 1;
    const int lr = lane & 15;
    const int lk = (lane >> 4) * 8;
    f32x4 acc[4][4] = {};

    for (int kt = 0; kt < KTILES; ++kt) {
        if (kt) __syncthreads();
#pragma unroll
        for (int p = 0; p < 8; ++p) {
            const int idx = p * 256 + tid;
            const int row = idx >> 4, ch = (idx & 15) * 8;
            uint4 v = make_uint4(0, 0, 0, 0);
            const int gr = M0 + row;
            if (gr < N_NODES)
                v = *(const uint4*)&A[(size_t)gr * K + kt * 128 + ch];
            *(uint4*)&As[row][ch] = v;
        }
#pragma unroll
        for (int p = 0; p < 8; ++p) {
            const int idx = p * 256 + tid;
            const int row = idx >> 4, ch = (idx & 15) * 8;
            *(uint4*)&Bs[row][ch] =
                *(const uint4*)&Bt[(size_t)(N0 + row) * K + kt * 128 + ch];
        }
        __syncthreads();
#pragma unroll
        for (int ks = 0; ks < 4; ++ks) {
            const int kof = ks * 32 + lk;
            bf16x8 af[4], bfr[4];
#pragma unroll
            for (int mi = 0; mi < 4; ++mi)
                af[mi] = *(const bf16x8*)&As[wm * 64 + mi * 16 + lr][kof];
#pragma unroll
            for (int ni = 0; ni < 4; ++ni)
                bfr[ni] = *(const bf16x8*)&Bs[wn * 64 + ni * 16 + lr][kof];
#pragma unroll
            for (int mi = 0; mi < 4; ++mi)
#pragma unroll
                for (int ni = 0; ni < 4; ++ni)
                    acc[mi][ni] = __builtin_amdgcn_mfma_f32_16x16x32_bf16(
                        af[mi], bfr[ni], acc[mi][ni], 0, 0, 0);
        }
    }
    __syncthreads();

#pragma unroll
    for (int ni = 0; ni < 4; ++ni) {
        const int cl = wn * 64 + ni * 16 + lr;
        const float bv = bias[N0 + cl];
        float ps = 0.f, pq = 0.f;
#pragma unroll
        for (int mi = 0; mi < 4; ++mi) {
            const int rbase = M0 + wm * 64 + mi * 16 + (lane >> 4) * 4;
#pragma unroll
            for (int r = 0; r < 4; ++r) {
                const int row = rbase + r;
                if (row < N_NODES) {
                    const float v = acc[mi][ni][r] + bv;
                    out[(size_t)row * Ntot + N0 + cl] = f2bf(v);
                    ps += v;
                    pq += v * v;
                }
            }
        }
        atomicAdd(&ls_sum[cl], ps);
        atomicAdd(&ls_sq[cl], pq);
    }
    __syncthreads();
    if (tid < 128) {
        unsafeAtomicAdd(&gsum[N0 + tid], ls_sum[tid]);
        unsafeAtomicAdd(&gsq[N0 + tid], ls_sq[tid]);
    }
}

// ===========================================================================
// GEMM2 with fused BN1+relu on A-staging: t2 = relu(bn1(t1)) @ W2t^T + b2.
// K=256 (2 k-tiles), Ntot=128 (gridDim.y==1). Staging computes
// f2bf(relu(fmaf(bf2f(t1),sc,sh))) -- bit-identical to the old bnapply1 pass.
// ===========================================================================
__global__ __launch_bounds__(256) void gemm2_bn_kernel(
    const ushort_t* __restrict__ A, const float* __restrict__ sc1,
    const float* __restrict__ sh1, const ushort_t* __restrict__ Bt,
    const float* __restrict__ bias, ushort_t* __restrict__ out,
    float* __restrict__ gsum, float* __restrict__ gsq)
{
    __shared__ ushort_t As[128][136];
    __shared__ ushort_t Bs[128][136];
    __shared__ float ls_sum[128], ls_sq[128];
    const int tid = threadIdx.x;
    const int M0 = blockIdx.x * 128;
    const int K = 256, Ntot = 128;
    if (tid < 128) { ls_sum[tid] = 0.f; ls_sq[tid] = 0.f; }
    const int lane = tid & 63, w = tid >> 6;
    const int wm = w >> 1, wn = w & 1;
    const int lr = lane & 15;
    const int lk = (lane >> 4) * 8;
    f32x4 acc[4][4] = {};

    for (int kt = 0; kt < 2; ++kt) {
        if (kt) __syncthreads();
#pragma unroll
        for (int p = 0; p < 8; ++p) {
            const int idx = p * 256 + tid;
            const int row = idx >> 4, ch = (idx & 15) * 8;
            const int col = kt * 128 + ch;
            uint4 v = make_uint4(0, 0, 0, 0);
            const int gr = M0 + row;
            if (gr < N_NODES) {
                const uint4 t = *(const uint4*)&A[(size_t)gr * K + col];
                float f[8];
                f[0] = bf2f(t.x & 0xffffu); f[1] = bf2f(t.x >> 16);
                f[2] = bf2f(t.y & 0xffffu); f[3] = bf2f(t.y >> 16);
                f[4] = bf2f(t.z & 0xffffu); f[5] = bf2f(t.z >> 16);
                f[6] = bf2f(t.w & 0xffffu); f[7] = bf2f(t.w >> 16);
                const float4 s0 = *(const float4*)&sc1[col];
                const float4 s1 = *(const float4*)&sc1[col + 4];
                const float4 h0 = *(const float4*)&sh1[col];
                const float4 h1 = *(const float4*)&sh1[col + 4];
                f[0] = fmaxf(fmaf(f[0], s0.x, h0.x), 0.f);
                f[1] = fmaxf(fmaf(f[1], s0.y, h0.y), 0.f);
                f[2] = fmaxf(fmaf(f[2], s0.z, h0.z), 0.f);
                f[3] = fmaxf(fmaf(f[3], s0.w, h0.w), 0.f);
                f[4] = fmaxf(fmaf(f[4], s1.x, h1.x), 0.f);
                f[5] = fmaxf(fmaf(f[5], s1.y, h1.y), 0.f);
                f[6] = fmaxf(fmaf(f[6], s1.z, h1.z), 0.f);
                f[7] = fmaxf(fmaf(f[7], s1.w, h1.w), 0.f);
                v.x = (uint_t)f2bf(f[0]) | ((uint_t)f2bf(f[1]) << 16);
                v.y = (uint_t)f2bf(f[2]) | ((uint_t)f2bf(f[3]) << 16);
                v.z = (uint_t)f2bf(f[4]) | ((uint_t)f2bf(f[5]) << 16);
                v.w = (uint_t)f2bf(f[6]) | ((uint_t)f2bf(f[7]) << 16);
            }
            *(uint4*)&As[row][ch] = v;
        }
#pragma unroll
        for (int p = 0; p < 8; ++p) {
            const int idx = p * 256 + tid;
            const int row = idx >> 4, ch = (idx & 15) * 8;
            *(uint4*)&Bs[row][ch] =
                *(const uint4*)&Bt[(size_t)row * K + kt * 128 + ch];
        }
        __syncthreads();
#pragma unroll
        for (int ks = 0; ks < 4; ++ks) {
            const int kof = ks * 32 + lk;
            bf16x8 af[4], bfr[4];
#pragma unroll
            for (int mi = 0; mi < 4; ++mi)
                af[mi] = *(const bf16x8*)&As[wm * 64 + mi * 16 + lr][kof];
#pragma unroll
            for (int ni = 0; ni < 4; ++ni)
                bfr[ni] = *(const bf16x8*)&Bs[wn * 64 + ni * 16 + lr][kof];
#pragma unroll
            for (int mi = 0; mi < 4; ++mi)
#pragma unroll
                for (int ni = 0; ni < 4; ++ni)
                    acc[mi][ni] = __builtin_amdgcn_mfma_f32_16x16x32_bf16(
                        af[mi], bfr[ni], acc[mi][ni], 0, 0, 0);
        }
    }
    __syncthreads();

#pragma unroll
    for (int ni = 0; ni < 4; ++ni) {
        const int cl = wn * 64 + ni * 16 + lr;
        const float bv = bias[cl];
        float ps = 0.f, pq = 0.f;
#pragma unroll
        for (int mi = 0; mi < 4; ++mi) {
            const int rbase = M0 + wm * 64 + mi * 16 + (lane >> 4) * 4;
#pragma unroll
            for (int r = 0; r < 4; ++r) {
                const int row = rbase + r;
                if (row < N_NODES) {
                    const float v = acc[mi][ni][r] + bv;
                    out[(size_t)row * Ntot + cl] = f2bf(v);
                    ps += v;
                    pq += v * v;
                }
            }
        }
        atomicAdd(&ls_sum[cl], ps);
        atomicAdd(&ls_sq[cl], pq);
    }
    __syncthreads();
    if (tid < 128) {
        unsafeAtomicAdd(&gsum[tid], ls_sum[tid]);
        unsafeAtomicAdd(&gsq[tid], ls_sq[tid]);
    }
}

// ---------------------------------------------------------------------------
__global__ void bnparam_kernel(const float* __restrict__ gsum,
                               const float* __restrict__ gsq,
                               const float* __restrict__ g,
                               const float* __restrict__ bt,
                               float* __restrict__ scale,
                               float* __restrict__ shift, int C)
{
    const int c = threadIdx.x;
    if (c < C) {
        const float inv_n = 1.0f / (float)N_NODES;
        const float mu = gsum[c] * inv_n;
        const float var = gsq[c] * inv_n - mu * mu;
        const float s = g[c] * rsqrtf(var + BN_EPS);
        scale[c] = s;
        shift[c] = bt[c] - mu * s;
    }
}

// ---------------------------------------------------------------------------
// Final BN2 apply (last layer only, no relu): t2 bf16 -> fp32 out
// ---------------------------------------------------------------------------
__global__ __launch_bounds__(256) void bnapply2_kernel(
    const ushort_t* __restrict__ t, const float* __restrict__ sc,
    const float* __restrict__ sh, float* __restrict__ outp)
{
    const size_t idx = (size_t)blockIdx.x * 256 + threadIdx.x;  // 8-elem idx
    const int c = (int)(idx & 15) * 8;
    const uint4 v = ((const uint4*)t)[idx];
    const float4 s0 = *(const float4*)&sc[c];
    const float4 s1 = *(const float4*)&sc[c + 4];
    const float4 h0 = *(const float4*)&sh[c];
    const float4 h1 = *(const float4*)&sh[c + 4];
    float4 r0, r1;
    r0.x = fmaf(bf2f(v.x & 0xffffu), s0.x, h0.x);
    r0.y = fmaf(bf2f(v.x >> 16),     s0.y, h0.y);
    r0.z = fmaf(bf2f(v.y & 0xffffu), s0.z, h0.z);
    r0.w = fmaf(bf2f(v.y >> 16),     s0.w, h0.w);
    r1.x = fmaf(bf2f(v.z & 0xffffu), s1.x, h1.x);
    r1.y = fmaf(bf2f(v.z >> 16),     s1.y, h1.y);
    r1.z = fmaf(bf2f(v.w & 0xffffu), s1.z, h1.z);
    r1.w = fmaf(bf2f(v.w >> 16),     s1.w, h1.w);
    *(float4*)&outp[idx * 8]     = r0;
    *(float4*)&outp[idx * 8 + 4] = r1;
}

// ---------------------------------------------------------------------------
extern "C" void kernel_launch(void* const* d_in, const int* in_sizes, int n_in,
                              void* d_out, int out_size, void* d_ws, size_t ws_size,
                              hipStream_t stream)
{
    const float* x         = (const float*)d_in[0];
    const int*   edge_index= (const int*)d_in[1];
    const float* edge_attr = (const float*)d_in[2];
    const float* eps       = (const float*)d_in[3];
    const float* We        = (const float*)d_in[4];
    const float* be        = (const float*)d_in[5];
    const float* W1        = (const float*)d_in[6];
    const float* b1        = (const float*)d_in[7];
    const float* g1        = (const float*)d_in[8];
    const float* bt1       = (const float*)d_in[9];
    const float* W2        = (const float*)d_in[10];
    const float* b2        = (const float*)d_in[11];
    const float* gbn       = (const float*)d_in[12];
    const float* bbn       = (const float*)d_in[13];
    float* out = (float*)d_out;

    float* ws = (float*)d_ws;
    const size_t ND = (size_t)N_NODES * D;        // 6.4M
    // ws layout (floats): ea_s | zbuf(bf16) | t2buf(bf16) | t1buf(bf16) | stats
    float* EAS  = ws;                              // 5,120,000 floats
    float* ZB   = EAS + (size_t)N_EDGES * 8;       // ND bf16 = ND/2 floats
    float* T2B  = ZB + ND / 2;                     // ND bf16
    float* T1B  = T2B + ND / 2;                    // N*256 bf16 = ND floats
    float* STATS = T1B + ND;
    float* gsum1 = STATS;               // 3*256
    float* gsq1  = gsum1 + 3 * 256;
    float* gsum2 = gsq1 + 3 * 256;      // 3*128
    float* gsq2  = gsum2 + 3 * 128;
    float* scale1 = gsq2 + 3 * 128;     // 256
    float* shift1 = scale1 + 256;
    float* sc2buf = shift1 + 256;       // 3*128 (per-layer BN2 scale)
    float* sh2buf = sc2buf + 3 * 128;   // 3*128

    ushort_t* zbuf  = (ushort_t*)ZB;
    ushort_t* t2buf = (ushort_t*)T2B;
    ushort_t* t1buf = (ushort_t*)T1B;

    // Transient sort scratch aliased into t1buf region (dead before gemm1 l0)
    int* hist   = (int*)T1B;
    int* scanA  = hist + N_NODES;
    int* bsum   = scanA + 50176;
    int* bscan  = bsum + 256;
    int* cursor = bscan + 256;

    // Persistent CSR + bf16 weights in d_out (overwritten by final bnapply2)
    int* srcp_s = (int*)d_out;                    // 640000
    int* excl   = srcp_s + N_EDGES;               // 50001
    ushort_t* W1t = (ushort_t*)((int*)d_out + 690008);  // [3][256][128]
    ushort_t* W2t = W1t + 3 * D2 * D;                    // [3][128][256]

    const int* srcp = edge_index;
    const int* dstp = edge_index + N_EDGES;

    hipMemsetAsync(STATS, 0, 2304 * sizeof(float), stream);
    hipMemsetAsync(hist, 0, N_NODES * sizeof(int), stream);

    const int EB = (N_EDGES + 255) / 256;
    const int NB = (N_NODES + 255) / 256;
    hist_kernel<<<EB, 256, 0, stream>>>(dstp, hist);
    scan1_kernel<<<NB, 256, 0, stream>>>(hist, scanA, bsum);
    scan2_kernel<<<1, 256, 0, stream>>>(bsum, bscan, NB);
    scan3_kernel<<<NB, 256, 0, stream>>>(hist, scanA, bscan, excl);
    hipMemcpyAsync(cursor, excl, N_NODES * sizeof(int),
                   hipMemcpyDeviceToDevice, stream);
    scatter_kernel<<<EB, 256, 0, stream>>>(srcp, dstp, edge_attr,
                                           cursor, srcp_s, EAS);

    wtrans_kernel<<<dim3(8, 4, 3), 256, 0, stream>>>(W1, W1t, D, D2);
    wtrans_kernel<<<dim3(4, 8, 3), 256, 0, stream>>>(W2, W2t, D2, D);

    for (int l = 0; l < 3; ++l) {
        if (l == 0) {
            agg_z_f32_kernel<<<N_NODES / 4, 256, 0, stream>>>(
                x, excl, srcp_s, EAS,
                We + (size_t)l * 8 * D, be + (size_t)l * D, eps + l, zbuf);
        } else {
            agg_z_bf16_kernel<<<N_NODES / 4, 256, 0, stream>>>(
                t2buf, sc2buf + (l - 1) * 128, sh2buf + (l - 1) * 128,
                excl, srcp_s, EAS,
                We + (size_t)l * 8 * D, be + (size_t)l * D, eps + l, zbuf);
        }

        dim3 grid1((N_NODES + 127) / 128, 2);
        gemm_bf16_kernel<1><<<grid1, 256, 0, stream>>>(
            zbuf, W1t + (size_t)l * D2 * D, b1 + (size_t)l * D2,
            t1buf, gsum1 + l * 256, gsq1 + l * 256);

        bnparam_kernel<<<1, 256, 0, stream>>>(
            gsum1 + l * 256, gsq1 + l * 256,
            g1 + (size_t)l * D2, bt1 + (size_t)l * D2, scale1, shift1, D2);

        dim3 grid2((N_NODES + 127) / 128, 1);
        gemm2_bn_kernel<<<grid2, 256, 0, stream>>>(
            t1buf, scale1, shift1,
            W2t + (size_t)l * D * D2, b2 + (size_t)l * D, t2buf,
            gsum2 + l * 128, gsq2 + l * 128);

        bnparam_kernel<<<1, 256, 0, stream>>>(
            gsum2 + l * 128, gsq2 + l * 128,
            gbn + (size_t)l * D, bbn + (size_t)l * D,
            sc2buf + l * 128, sh2buf + l * 128, D);
    }

    bnapply2_kernel<<<(N_NODES * D / 8) / 256, 256, 0, stream>>>(
        t2buf, sc2buf + 2 * 128, sh2buf + 2 * 128, out);
}

// Round 8
// 656.545 us; speedup vs baseline: 3.5484x; 1.0292x over previous
//
#include <hip/hip_runtime.h>

#define N_NODES 50000
#define N_EDGES 640000
#define D 128
#define D2 256
#define BN_EPS 1e-5f

typedef unsigned short ushort_t;
typedef unsigned int uint_t;

using bf16x8 = __attribute__((ext_vector_type(8))) short;
using f32x4  = __attribute__((ext_vector_type(4))) float;

__device__ inline ushort_t f2bf(float f) {
    uint_t u = __builtin_bit_cast(uint_t, f);
    u = (u + 0x7fffu + ((u >> 16) & 1u)) >> 16;   // RTNE
    return (ushort_t)u;
}
__device__ inline float bf2f(uint_t bits_lo16) {
    return __builtin_bit_cast(float, bits_lo16 << 16);
}

// ===========================================================================
// Preprocessing: CSR permutation of edges by dst (once per call).
// scatter also pre-permutes edge_attr into ea_s.
// ===========================================================================
__global__ __launch_bounds__(256) void hist_kernel(
    const int* __restrict__ dst, int* __restrict__ hist)
{
    const int e = blockIdx.x * 256 + threadIdx.x;
    if (e < N_EDGES) atomicAdd(&hist[dst[e]], 1);
}

__global__ __launch_bounds__(256) void scan1_kernel(
    const int* __restrict__ hist, int* __restrict__ scanA,
    int* __restrict__ bsum)
{
    __shared__ int sm[256];
    const int t = threadIdx.x;
    const int idx = blockIdx.x * 256 + t;
    int val = (idx < N_NODES) ? hist[idx] : 0;
    sm[t] = val;
    __syncthreads();
#pragma unroll
    for (int off = 1; off < 256; off <<= 1) {
        const int add = (t >= off) ? sm[t - off] : 0;
        __syncthreads();
        val += add;
        sm[t] = val;
        __syncthreads();
    }
    scanA[idx] = val;
    if (t == 255) bsum[blockIdx.x] = val;
}

__global__ __launch_bounds__(256) void scan2_kernel(
    const int* __restrict__ bsum, int* __restrict__ bscan, int nb)
{
    __shared__ int sm[256];
    const int t = threadIdx.x;
    int val = (t < nb) ? bsum[t] : 0;
    sm[t] = val;
    __syncthreads();
#pragma unroll
    for (int off = 1; off < 256; off <<= 1) {
        const int add = (t >= off) ? sm[t - off] : 0;
        __syncthreads();
        val += add;
        sm[t] = val;
        __syncthreads();
    }
    bscan[t] = val;
}

__global__ __launch_bounds__(256) void scan3_kernel(
    const int* __restrict__ hist, const int* __restrict__ scanA,
    const int* __restrict__ bscan, int* __restrict__ excl)
{
    const int idx = blockIdx.x * 256 + threadIdx.x;
    if (idx < N_NODES) {
        const int carry = blockIdx.x ? bscan[blockIdx.x - 1] : 0;
        const int incl = scanA[idx] + carry;
        excl[idx] = incl - hist[idx];
        if (idx == N_NODES - 1) excl[N_NODES] = incl;
    }
}

__global__ __launch_bounds__(256) void scatter_kernel(
    const int* __restrict__ src, const int* __restrict__ dst,
    const float* __restrict__ ea, int* __restrict__ cursor,
    int* __restrict__ srcp_s, float* __restrict__ ea_s)
{
    const int e = blockIdx.x * 256 + threadIdx.x;
    if (e < N_EDGES) {
        const int t = dst[e];
        const int p = atomicAdd(&cursor[t], 1);
        srcp_s[p] = src[e];
        *(float4*)&ea_s[(size_t)p * 8]     = *(const float4*)&ea[(size_t)e * 8];
        *(float4*)&ea_s[(size_t)p * 8 + 4] = *(const float4*)&ea[(size_t)e * 8 + 4];
    }
}

// ===========================================================================
// W transpose + bf16 convert: in fp32 [L][K][Nt] -> out bf16 [L][Nt][K]
// ===========================================================================
__global__ __launch_bounds__(256) void wtrans_kernel(
    const float* __restrict__ in, ushort_t* __restrict__ out, int K, int Nt)
{
    __shared__ float tile[32][33];
    const int l = blockIdx.z;
    in  += (size_t)l * K * Nt;
    out += (size_t)l * K * Nt;
    const int n0 = blockIdx.x * 32, k0 = blockIdx.y * 32;
    const int tx = threadIdx.x & 31, ty = threadIdx.x >> 5;   // 32 x 8
#pragma unroll
    for (int i = 0; i < 32; i += 8)
        tile[ty + i][tx] = in[(size_t)(k0 + ty + i) * Nt + n0 + tx];
    __syncthreads();
#pragma unroll
    for (int i = 0; i < 32; i += 8)
        out[(size_t)(n0 + ty + i) * K + k0 + tx] = f2bf(tile[tx][ty + i]);
}

// ===========================================================================
// Aggregation. One wave per node; 4 groups of 16 lanes each own a different
// edge position (q ≡ grp mod 4); lane owns 8 dims. Wave pre-loads the first
// 64 src indices into registers. CRITICAL (round-7 lesson): all __shfl reads
// must execute with ALL lanes active — trip count is wave-uniform, so the hot
// loop runs niter-1 full iterations (both slots valid for every group), and
// the last iteration does its (clamped) shuffles BEFORE the divergent
// load/accum guards. Accumulation order per group is ascending in p ->
// bit-identical to round 6.
// ===========================================================================
__device__ __forceinline__ void msg_accum(
    const float* __restrict__ hv, const float* __restrict__ eav,
    const float (&wv)[8][8], const float* __restrict__ bev,
    float* __restrict__ acc)
{
    float m[8];
#pragma unroll
    for (int j = 0; j < 8; ++j) m[j] = bev[j];
#pragma unroll
    for (int k = 0; k < 8; ++k)
#pragma unroll
        for (int j = 0; j < 8; ++j)
            m[j] = fmaf(eav[k], wv[k][j], m[j]);
#pragma unroll
    for (int j = 0; j < 8; ++j)
        acc[j] += fmaxf(hv[j] + m[j], 0.f);
}

__device__ __forceinline__ void unpack_bn_relu(
    const uint4 v, const float* __restrict__ scv,
    const float* __restrict__ shv, float* __restrict__ hv)
{
    float f[8];
    f[0] = bf2f(v.x & 0xffffu); f[1] = bf2f(v.x >> 16);
    f[2] = bf2f(v.y & 0xffffu); f[3] = bf2f(v.y >> 16);
    f[4] = bf2f(v.z & 0xffffu); f[5] = bf2f(v.z >> 16);
    f[6] = bf2f(v.w & 0xffffu); f[7] = bf2f(v.w >> 16);
#pragma unroll
    for (int j = 0; j < 8; ++j)
        hv[j] = fmaxf(fmaf(f[j], scv[j], shv[j]), 0.f);
}

__device__ __forceinline__ void store_z(
    ushort_t* __restrict__ z, int node, int d0, float epsv,
    const float* __restrict__ hn, const float* __restrict__ acc)
{
    uint_t w[8];
#pragma unroll
    for (int j = 0; j < 8; ++j)
        w[j] = (uint_t)f2bf(fmaf(epsv, hn[j], acc[j]));
    uint4 o;
    o.x = w[0] | (w[1] << 16);
    o.y = w[2] | (w[3] << 16);
    o.z = w[4] | (w[5] << 16);
    o.w = w[6] | (w[7] << 16);
    *(uint4*)&z[(size_t)node * D + d0] = o;
}

// Layer 0: gather fp32 x rows.
__global__ __launch_bounds__(256) void agg_z_f32_kernel(
    const float* __restrict__ h, const int* __restrict__ excl,
    const int* __restrict__ srcp_s, const float* __restrict__ ea_s,
    const float* __restrict__ We_l, const float* __restrict__ be_l,
    const float* __restrict__ eps_l, ushort_t* __restrict__ z)
{
    const int lane = threadIdx.x & 63;
    const int wave = threadIdx.x >> 6;
    const int node = blockIdx.x * 4 + wave;
    const int grp  = lane >> 4;
    const int gl   = lane & 15;
    const int d0   = gl * 8;

    float wv[8][8];
#pragma unroll
    for (int k = 0; k < 8; ++k) {
        *(float4*)&wv[k][0] = *(const float4*)&We_l[k * D + d0];
        *(float4*)&wv[k][4] = *(const float4*)&We_l[k * D + d0 + 4];
    }
    float bev[8];
    *(float4*)&bev[0] = *(const float4*)&be_l[d0];
    *(float4*)&bev[4] = *(const float4*)&be_l[d0 + 4];

    const int p0 = excl[node];
    const int p1 = excl[node + 1];
    const int deg = p1 - p0;
    const int scached = (lane < deg) ? srcp_s[p0 + lane] : 0;
    const int nmain = deg < 64 ? deg : 64;

    float acc[8] = {0.f, 0.f, 0.f, 0.f, 0.f, 0.f, 0.f, 0.f};

    if (deg > 0) {          // wave-uniform branch
        const int niter = (nmain + 7) >> 3;   // wave-uniform trip count
        int qA = grp, qB = grp + 4;
        float eA[8], hA[8], eB[8], hB[8];
        for (int it = 0; it < niter - 1; ++it) {
            // both qA,qB < nmain for ALL groups here -> all lanes active
            const int sA = __shfl(scached, qA);
            const int sB = __shfl(scached, qB);
            *(float4*)&eA[0] = *(const float4*)&ea_s[(size_t)(p0 + qA) * 8];
            *(float4*)&eA[4] = *(const float4*)&ea_s[(size_t)(p0 + qA) * 8 + 4];
            *(float4*)&hA[0] = *(const float4*)&h[(size_t)sA * D + d0];
            *(float4*)&hA[4] = *(const float4*)&h[(size_t)sA * D + d0 + 4];
            *(float4*)&eB[0] = *(const float4*)&ea_s[(size_t)(p0 + qB) * 8];
            *(float4*)&eB[4] = *(const float4*)&ea_s[(size_t)(p0 + qB) * 8 + 4];
            *(float4*)&hB[0] = *(const float4*)&h[(size_t)sB * D + d0];
            *(float4*)&hB[4] = *(const float4*)&h[(size_t)sB * D + d0 + 4];
            msg_accum(hA, eA, wv, bev, acc);
            msg_accum(hB, eB, wv, bev, acc);
            qA += 8; qB += 8;
        }
        // last iteration: shuffles BEFORE divergent guards (clamped lane)
        const int cA = (qA < nmain) ? qA : 0;
        const int cB = (qB < nmain) ? qB : 0;
        const int sA = __shfl(scached, cA);
        const int sB = __shfl(scached, cB);
        if (qA < nmain) {
            *(float4*)&eA[0] = *(const float4*)&ea_s[(size_t)(p0 + qA) * 8];
            *(float4*)&eA[4] = *(const float4*)&ea_s[(size_t)(p0 + qA) * 8 + 4];
            *(float4*)&hA[0] = *(const float4*)&h[(size_t)sA * D + d0];
            *(float4*)&hA[4] = *(const float4*)&h[(size_t)sA * D + d0 + 4];
            msg_accum(hA, eA, wv, bev, acc);
        }
        if (qB < nmain) {
            *(float4*)&eB[0] = *(const float4*)&ea_s[(size_t)(p0 + qB) * 8];
            *(float4*)&eB[4] = *(const float4*)&ea_s[(size_t)(p0 + qB) * 8 + 4];
            *(float4*)&hB[0] = *(const float4*)&h[(size_t)sB * D + d0];
            *(float4*)&hB[4] = *(const float4*)&h[(size_t)sB * D + d0 + 4];
            msg_accum(hB, eB, wv, bev, acc);
        }
    }
    // rare tail: deg > 64 (chained loads, no shuffles, ascending order)
    for (int p = p0 + 64 + grp; p < p1; p += 4) {
        const int s = srcp_s[p];
        float eT[8], hT[8];
        *(float4*)&eT[0] = *(const float4*)&ea_s[(size_t)p * 8];
        *(float4*)&eT[4] = *(const float4*)&ea_s[(size_t)p * 8 + 4];
        *(float4*)&hT[0] = *(const float4*)&h[(size_t)s * D + d0];
        *(float4*)&hT[4] = *(const float4*)&h[(size_t)s * D + d0 + 4];
        msg_accum(hT, eT, wv, bev, acc);
    }

#pragma unroll
    for (int j = 0; j < 8; ++j) {
        acc[j] += __shfl_xor(acc[j], 16);
        acc[j] += __shfl_xor(acc[j], 32);
    }

    if (grp == 0) {
        float hn[8];
        *(float4*)&hn[0] = *(const float4*)&h[(size_t)node * D + d0];
        *(float4*)&hn[4] = *(const float4*)&h[(size_t)node * D + d0 + 4];
        store_z(z, node, d0, 1.0f + eps_l[0], hn, acc);
    }
}

// Layers 1,2: gather bf16 t2 rows, apply BN2+relu inline.
__global__ __launch_bounds__(256) void agg_z_bf16_kernel(
    const ushort_t* __restrict__ t2, const float* __restrict__ sc2,
    const float* __restrict__ sh2, const int* __restrict__ excl,
    const int* __restrict__ srcp_s, const float* __restrict__ ea_s,
    const float* __restrict__ We_l, const float* __restrict__ be_l,
    const float* __restrict__ eps_l, ushort_t* __restrict__ z)
{
    const int lane = threadIdx.x & 63;
    const int wave = threadIdx.x >> 6;
    const int node = blockIdx.x * 4 + wave;
    const int grp  = lane >> 4;
    const int gl   = lane & 15;
    const int d0   = gl * 8;

    float wv[8][8];
#pragma unroll
    for (int k = 0; k < 8; ++k) {
        *(float4*)&wv[k][0] = *(const float4*)&We_l[k * D + d0];
        *(float4*)&wv[k][4] = *(const float4*)&We_l[k * D + d0 + 4];
    }
    float bev[8], scv[8], shv[8];
    *(float4*)&bev[0] = *(const float4*)&be_l[d0];
    *(float4*)&bev[4] = *(const float4*)&be_l[d0 + 4];
    *(float4*)&scv[0] = *(const float4*)&sc2[d0];
    *(float4*)&scv[4] = *(const float4*)&sc2[d0 + 4];
    *(float4*)&shv[0] = *(const float4*)&sh2[d0];
    *(float4*)&shv[4] = *(const float4*)&sh2[d0 + 4];

    const int p0 = excl[node];
    const int p1 = excl[node + 1];
    const int deg = p1 - p0;
    const int scached = (lane < deg) ? srcp_s[p0 + lane] : 0;
    const int nmain = deg < 64 ? deg : 64;

    float acc[8] = {0.f, 0.f, 0.f, 0.f, 0.f, 0.f, 0.f, 0.f};

    if (deg > 0) {          // wave-uniform branch
        const int niter = (nmain + 7) >> 3;
        int qA = grp, qB = grp + 4;
        float eA[8], eB[8], hA[8], hB[8];
        uint4 vA, vB;
        for (int it = 0; it < niter - 1; ++it) {
            const int sA = __shfl(scached, qA);
            const int sB = __shfl(scached, qB);
            *(float4*)&eA[0] = *(const float4*)&ea_s[(size_t)(p0 + qA) * 8];
            *(float4*)&eA[4] = *(const float4*)&ea_s[(size_t)(p0 + qA) * 8 + 4];
            vA = *(const uint4*)&t2[(size_t)sA * D + d0];
            *(float4*)&eB[0] = *(const float4*)&ea_s[(size_t)(p0 + qB) * 8];
            *(float4*)&eB[4] = *(const float4*)&ea_s[(size_t)(p0 + qB) * 8 + 4];
            vB = *(const uint4*)&t2[(size_t)sB * D + d0];
            unpack_bn_relu(vA, scv, shv, hA);
            msg_accum(hA, eA, wv, bev, acc);
            unpack_bn_relu(vB, scv, shv, hB);
            msg_accum(hB, eB, wv, bev, acc);
            qA += 8; qB += 8;
        }
        const int cA = (qA < nmain) ? qA : 0;
        const int cB = (qB < nmain) ? qB : 0;
        const int sA = __shfl(scached, cA);
        const int sB = __shfl(scached, cB);
        if (qA < nmain) {
            *(float4*)&eA[0] = *(const float4*)&ea_s[(size_t)(p0 + qA) * 8];
            *(float4*)&eA[4] = *(const float4*)&ea_s[(size_t)(p0 + qA) * 8 + 4];
            vA = *(const uint4*)&t2[(size_t)sA * D + d0];
            unpack_bn_relu(vA, scv, shv, hA);
            msg_accum(hA, eA, wv, bev, acc);
        }
        if (qB < nmain) {
            *(float4*)&eB[0] = *(const float4*)&ea_s[(size_t)(p0 + qB) * 8];
            *(float4*)&eB[4] = *(const float4*)&ea_s[(size_t)(p0 + qB) * 8 + 4];
            vB = *(const uint4*)&t2[(size_t)sB * D + d0];
            unpack_bn_relu(vB, scv, shv, hB);
            msg_accum(hB, eB, wv, bev, acc);
        }
    }
    // rare tail: deg > 64
    for (int p = p0 + 64 + grp; p < p1; p += 4) {
        const int s = srcp_s[p];
        float eT[8], hT[8];
        *(float4*)&eT[0] = *(const float4*)&ea_s[(size_t)p * 8];
        *(float4*)&eT[4] = *(const float4*)&ea_s[(size_t)p * 8 + 4];
        const uint4 vT = *(const uint4*)&t2[(size_t)s * D + d0];
        unpack_bn_relu(vT, scv, shv, hT);
        msg_accum(hT, eT, wv, bev, acc);
    }

#pragma unroll
    for (int j = 0; j < 8; ++j) {
        acc[j] += __shfl_xor(acc[j], 16);
        acc[j] += __shfl_xor(acc[j], 32);
    }

    if (grp == 0) {
        const uint4 vN = *(const uint4*)&t2[(size_t)node * D + d0];
        float hn[8];
        unpack_bn_relu(vN, scv, shv, hn);
        store_z(z, node, d0, 1.0f + eps_l[0], hn, acc);
    }
}

// ===========================================================================
// bf16 MFMA GEMM1: t1 = z @ W1t^T + b1. BM=BN=BK=128, 4 waves (2x2).
// ===========================================================================
template<int KTILES>
__global__ __launch_bounds__(256) void gemm_bf16_kernel(
    const ushort_t* __restrict__ A, const ushort_t* __restrict__ Bt,
    const float* __restrict__ bias, ushort_t* __restrict__ out,
    float* __restrict__ gsum, float* __restrict__ gsq)
{
    __shared__ ushort_t As[128][136];
    __shared__ ushort_t Bs[128][136];
    __shared__ float ls_sum[128], ls_sq[128];
    const int tid = threadIdx.x;
    const int M0 = blockIdx.x * 128;
    const int N0 = blockIdx.y * 128;
    const int Ntot = gridDim.y * 128;
    const int K = KTILES * 128;
    if (tid < 128) { ls_sum[tid] = 0.f; ls_sq[tid] = 0.f; }
    const int lane = tid & 63, w = tid >> 6;
    const int wm = w >> 1, wn = w & 1;
    const int lr = lane & 15;
    const int lk = (lane >> 4) * 8;
    f32x4 acc[4][4] = {};

    for (int kt = 0; kt < KTILES; ++kt) {
        if (kt) __syncthreads();
#pragma unroll
        for (int p = 0; p < 8; ++p) {
            const int idx = p * 256 + tid;
            const int row = idx >> 4, ch = (idx & 15) * 8;
            uint4 v = make_uint4(0, 0, 0, 0);
            const int gr = M0 + row;
            if (gr < N_NODES)
                v = *(const uint4*)&A[(size_t)gr * K + kt * 128 + ch];
            *(uint4*)&As[row][ch] = v;
        }
#pragma unroll
        for (int p = 0; p < 8; ++p) {
            const int idx = p * 256 + tid;
            const int row = idx >> 4, ch = (idx & 15) * 8;
            *(uint4*)&Bs[row][ch] =
                *(const uint4*)&Bt[(size_t)(N0 + row) * K + kt * 128 + ch];
        }
        __syncthreads();
#pragma unroll
        for (int ks = 0; ks < 4; ++ks) {
            const int kof = ks * 32 + lk;
            bf16x8 af[4], bfr[4];
#pragma unroll
            for (int mi = 0; mi < 4; ++mi)
                af[mi] = *(const bf16x8*)&As[wm * 64 + mi * 16 + lr][kof];
#pragma unroll
            for (int ni = 0; ni < 4; ++ni)
                bfr[ni] = *(const bf16x8*)&Bs[wn * 64 + ni * 16 + lr][kof];
#pragma unroll
            for (int mi = 0; mi < 4; ++mi)
#pragma unroll
                for (int ni = 0; ni < 4; ++ni)
                    acc[mi][ni] = __builtin_amdgcn_mfma_f32_16x16x32_bf16(
                        af[mi], bfr[ni], acc[mi][ni], 0, 0, 0);
        }
    }
    __syncthreads();

#pragma unroll
    for (int ni = 0; ni < 4; ++ni) {
        const int cl = wn * 64 + ni * 16 + lr;
        const float bv = bias[N0 + cl];
        float ps = 0.f, pq = 0.f;
#pragma unroll
        for (int mi = 0; mi < 4; ++mi) {
            const int rbase = M0 + wm * 64 + mi * 16 + (lane >> 4) * 4;
#pragma unroll
            for (int r = 0; r < 4; ++r) {
                const int row = rbase + r;
                if (row < N_NODES) {
                    const float v = acc[mi][ni][r] + bv;
                    out[(size_t)row * Ntot + N0 + cl] = f2bf(v);
                    ps += v;
                    pq += v * v;
                }
            }
        }
        atomicAdd(&ls_sum[cl], ps);
        atomicAdd(&ls_sq[cl], pq);
    }
    __syncthreads();
    if (tid < 128) {
        unsafeAtomicAdd(&gsum[N0 + tid], ls_sum[tid]);
        unsafeAtomicAdd(&gsq[N0 + tid], ls_sq[tid]);
    }
}

// ===========================================================================
// GEMM2 with fused BN1+relu on A-staging: t2 = relu(bn1(t1)) @ W2t^T + b2.
// ===========================================================================
__global__ __launch_bounds__(256) void gemm2_bn_kernel(
    const ushort_t* __restrict__ A, const float* __restrict__ sc1,
    const float* __restrict__ sh1, const ushort_t* __restrict__ Bt,
    const float* __restrict__ bias, ushort_t* __restrict__ out,
    float* __restrict__ gsum, float* __restrict__ gsq)
{
    __shared__ ushort_t As[128][136];
    __shared__ ushort_t Bs[128][136];
    __shared__ float ls_sum[128], ls_sq[128];
    const int tid = threadIdx.x;
    const int M0 = blockIdx.x * 128;
    const int K = 256, Ntot = 128;
    if (tid < 128) { ls_sum[tid] = 0.f; ls_sq[tid] = 0.f; }
    const int lane = tid & 63, w = tid >> 6;
    const int wm = w >> 1, wn = w & 1;
    const int lr = lane & 15;
    const int lk = (lane >> 4) * 8;
    f32x4 acc[4][4] = {};

    for (int kt = 0; kt < 2; ++kt) {
        if (kt) __syncthreads();
#pragma unroll
        for (int p = 0; p < 8; ++p) {
            const int idx = p * 256 + tid;
            const int row = idx >> 4, ch = (idx & 15) * 8;
            const int col = kt * 128 + ch;
            uint4 v = make_uint4(0, 0, 0, 0);
            const int gr = M0 + row;
            if (gr < N_NODES) {
                const uint4 t = *(const uint4*)&A[(size_t)gr * K + col];
                float f[8];
                f[0] = bf2f(t.x & 0xffffu); f[1] = bf2f(t.x >> 16);
                f[2] = bf2f(t.y & 0xffffu); f[3] = bf2f(t.y >> 16);
                f[4] = bf2f(t.z & 0xffffu); f[5] = bf2f(t.z >> 16);
                f[6] = bf2f(t.w & 0xffffu); f[7] = bf2f(t.w >> 16);
                const float4 s0 = *(const float4*)&sc1[col];
                const float4 s1 = *(const float4*)&sc1[col + 4];
                const float4 h0 = *(const float4*)&sh1[col];
                const float4 h1 = *(const float4*)&sh1[col + 4];
                f[0] = fmaxf(fmaf(f[0], s0.x, h0.x), 0.f);
                f[1] = fmaxf(fmaf(f[1], s0.y, h0.y), 0.f);
                f[2] = fmaxf(fmaf(f[2], s0.z, h0.z), 0.f);
                f[3] = fmaxf(fmaf(f[3], s0.w, h0.w), 0.f);
                f[4] = fmaxf(fmaf(f[4], s1.x, h1.x), 0.f);
                f[5] = fmaxf(fmaf(f[5], s1.y, h1.y), 0.f);
                f[6] = fmaxf(fmaf(f[6], s1.z, h1.z), 0.f);
                f[7] = fmaxf(fmaf(f[7], s1.w, h1.w), 0.f);
                v.x = (uint_t)f2bf(f[0]) | ((uint_t)f2bf(f[1]) << 16);
                v.y = (uint_t)f2bf(f[2]) | ((uint_t)f2bf(f[3]) << 16);
                v.z = (uint_t)f2bf(f[4]) | ((uint_t)f2bf(f[5]) << 16);
                v.w = (uint_t)f2bf(f[6]) | ((uint_t)f2bf(f[7]) << 16);
            }
            *(uint4*)&As[row][ch] = v;
        }
#pragma unroll
        for (int p = 0; p < 8; ++p) {
            const int idx = p * 256 + tid;
            const int row = idx >> 4, ch = (idx & 15) * 8;
            *(uint4*)&Bs[row][ch] =
                *(const uint4*)&Bt[(size_t)row * K + kt * 128 + ch];
        }
        __syncthreads();
#pragma unroll
        for (int ks = 0; ks < 4; ++ks) {
            const int kof = ks * 32 + lk;
            bf16x8 af[4], bfr[4];
#pragma unroll
            for (int mi = 0; mi < 4; ++mi)
                af[mi] = *(const bf16x8*)&As[wm * 64 + mi * 16 + lr][kof];
#pragma unroll
            for (int ni = 0; ni < 4; ++ni)
                bfr[ni] = *(const bf16x8*)&Bs[wn * 64 + ni * 16 + lr][kof];
#pragma unroll
            for (int mi = 0; mi < 4; ++mi)
#pragma unroll
                for (int ni = 0; ni < 4; ++ni)
                    acc[mi][ni] = __builtin_amdgcn_mfma_f32_16x16x32_bf16(
                        af[mi], bfr[ni], acc[mi][ni], 0, 0, 0);
        }
    }
    __syncthreads();

#pragma unroll
    for (int ni = 0; ni < 4; ++ni) {
        const int cl = wn * 64 + ni * 16 + lr;
        const float bv = bias[cl];
        float ps = 0.f, pq = 0.f;
#pragma unroll
        for (int mi = 0; mi < 4; ++mi) {
            const int rbase = M0 + wm * 64 + mi * 16 + (lane >> 4) * 4;
#pragma unroll
            for (int r = 0; r < 4; ++r) {
                const int row = rbase + r;
                if (row < N_NODES) {
                    const float v = acc[mi][ni][r] + bv;
                    out[(size_t)row * Ntot + cl] = f2bf(v);
                    ps += v;
                    pq += v * v;
                }
            }
        }
        atomicAdd(&ls_sum[cl], ps);
        atomicAdd(&ls_sq[cl], pq);
    }
    __syncthreads();
    if (tid < 128) {
        unsafeAtomicAdd(&gsum[tid], ls_sum[tid]);
        unsafeAtomicAdd(&gsq[tid], ls_sq[tid]);
    }
}

// ---------------------------------------------------------------------------
__global__ void bnparam_kernel(const float* __restrict__ gsum,
                               const float* __restrict__ gsq,
                               const float* __restrict__ g,
                               const float* __restrict__ bt,
                               float* __restrict__ scale,
                               float* __restrict__ shift, int C)
{
    const int c = threadIdx.x;
    if (c < C) {
        const float inv_n = 1.0f / (float)N_NODES;
        const float mu = gsum[c] * inv_n;
        const float var = gsq[c] * inv_n - mu * mu;
        const float s = g[c] * rsqrtf(var + BN_EPS);
        scale[c] = s;
        shift[c] = bt[c] - mu * s;
    }
}

// ---------------------------------------------------------------------------
// Final BN2 apply (last layer only, no relu): t2 bf16 -> fp32 out
// ---------------------------------------------------------------------------
__global__ __launch_bounds__(256) void bnapply2_kernel(
    const ushort_t* __restrict__ t, const float* __restrict__ sc,
    const float* __restrict__ sh, float* __restrict__ outp)
{
    const size_t idx = (size_t)blockIdx.x * 256 + threadIdx.x;  // 8-elem idx
    const int c = (int)(idx & 15) * 8;
    const uint4 v = ((const uint4*)t)[idx];
    const float4 s0 = *(const float4*)&sc[c];
    const float4 s1 = *(const float4*)&sc[c + 4];
    const float4 h0 = *(const float4*)&sh[c];
    const float4 h1 = *(const float4*)&sh[c + 4];
    float4 r0, r1;
    r0.x = fmaf(bf2f(v.x & 0xffffu), s0.x, h0.x);
    r0.y = fmaf(bf2f(v.x >> 16),     s0.y, h0.y);
    r0.z = fmaf(bf2f(v.y & 0xffffu), s0.z, h0.z);
    r0.w = fmaf(bf2f(v.y >> 16),     s0.w, h0.w);
    r1.x = fmaf(bf2f(v.z & 0xffffu), s1.x, h1.x);
    r1.y = fmaf(bf2f(v.z >> 16),     s1.y, h1.y);
    r1.z = fmaf(bf2f(v.w & 0xffffu), s1.z, h1.z);
    r1.w = fmaf(bf2f(v.w >> 16),     s1.w, h1.w);
    *(float4*)&outp[idx * 8]     = r0;
    *(float4*)&outp[idx * 8 + 4] = r1;
}

// ---------------------------------------------------------------------------
extern "C" void kernel_launch(void* const* d_in, const int* in_sizes, int n_in,
                              void* d_out, int out_size, void* d_ws, size_t ws_size,
                              hipStream_t stream)
{
    const float* x         = (const float*)d_in[0];
    const int*   edge_index= (const int*)d_in[1];
    const float* edge_attr = (const float*)d_in[2];
    const float* eps       = (const float*)d_in[3];
    const float* We        = (const float*)d_in[4];
    const float* be        = (const float*)d_in[5];
    const float* W1        = (const float*)d_in[6];
    const float* b1        = (const float*)d_in[7];
    const float* g1        = (const float*)d_in[8];
    const float* bt1       = (const float*)d_in[9];
    const float* W2        = (const float*)d_in[10];
    const float* b2        = (const float*)d_in[11];
    const float* gbn       = (const float*)d_in[12];
    const float* bbn       = (const float*)d_in[13];
    float* out = (float*)d_out;

    float* ws = (float*)d_ws;
    const size_t ND = (size_t)N_NODES * D;        // 6.4M
    // ws layout (floats): ea_s | zbuf(bf16) | t2buf(bf16) | t1buf(bf16) | stats
    float* EAS  = ws;                              // 5,120,000 floats
    float* ZB   = EAS + (size_t)N_EDGES * 8;       // ND bf16 = ND/2 floats
    float* T2B  = ZB + ND / 2;                     // ND bf16
    float* T1B  = T2B + ND / 2;                    // N*256 bf16 = ND floats
    float* STATS = T1B + ND;
    float* gsum1 = STATS;               // 3*256
    float* gsq1  = gsum1 + 3 * 256;
    float* gsum2 = gsq1 + 3 * 256;      // 3*128
    float* gsq2  = gsum2 + 3 * 128;
    float* scale1 = gsq2 + 3 * 128;     // 256
    float* shift1 = scale1 + 256;
    float* sc2buf = shift1 + 256;       // 3*128 (per-layer BN2 scale)
    float* sh2buf = sc2buf + 3 * 128;   // 3*128

    ushort_t* zbuf  = (ushort_t*)ZB;
    ushort_t* t2buf = (ushort_t*)T2B;
    ushort_t* t1buf = (ushort_t*)T1B;

    // Transient sort scratch aliased into t1buf region (dead before gemm1 l0)
    int* hist   = (int*)T1B;
    int* scanA  = hist + N_NODES;
    int* bsum   = scanA + 50176;
    int* bscan  = bsum + 256;
    int* cursor = bscan + 256;

    // Persistent CSR + bf16 weights in d_out (overwritten by final bnapply2)
    int* srcp_s = (int*)d_out;                    // 640000
    int* excl   = srcp_s + N_EDGES;               // 50001
    ushort_t* W1t = (ushort_t*)((int*)d_out + 690008);  // [3][256][128]
    ushort_t* W2t = W1t + 3 * D2 * D;                    // [3][128][256]

    const int* srcp = edge_index;
    const int* dstp = edge_index + N_EDGES;

    hipMemsetAsync(STATS, 0, 2304 * sizeof(float), stream);
    hipMemsetAsync(hist, 0, N_NODES * sizeof(int), stream);

    const int EB = (N_EDGES + 255) / 256;
    const int NB = (N_NODES + 255) / 256;
    hist_kernel<<<EB, 256, 0, stream>>>(dstp, hist);
    scan1_kernel<<<NB, 256, 0, stream>>>(hist, scanA, bsum);
    scan2_kernel<<<1, 256, 0, stream>>>(bsum, bscan, NB);
    scan3_kernel<<<NB, 256, 0, stream>>>(hist, scanA, bscan, excl);
    hipMemcpyAsync(cursor, excl, N_NODES * sizeof(int),
                   hipMemcpyDeviceToDevice, stream);
    scatter_kernel<<<EB, 256, 0, stream>>>(srcp, dstp, edge_attr,
                                           cursor, srcp_s, EAS);

    wtrans_kernel<<<dim3(8, 4, 3), 256, 0, stream>>>(W1, W1t, D, D2);
    wtrans_kernel<<<dim3(4, 8, 3), 256, 0, stream>>>(W2, W2t, D2, D);

    for (int l = 0; l < 3; ++l) {
        if (l == 0) {
            agg_z_f32_kernel<<<N_NODES / 4, 256, 0, stream>>>(
                x, excl, srcp_s, EAS,
                We + (size_t)l * 8 * D, be + (size_t)l * D, eps + l, zbuf);
        } else {
            agg_z_bf16_kernel<<<N_NODES / 4, 256, 0, stream>>>(
                t2buf, sc2buf + (l - 1) * 128, sh2buf + (l - 1) * 128,
                excl, srcp_s, EAS,
                We + (size_t)l * 8 * D, be + (size_t)l * D, eps + l, zbuf);
        }

        dim3 grid1((N_NODES + 127) / 128, 2);
        gemm_bf16_kernel<1><<<grid1, 256, 0, stream>>>(
            zbuf, W1t + (size_t)l * D2 * D, b1 + (size_t)l * D2,
            t1buf, gsum1 + l * 256, gsq1 + l * 256);

        bnparam_kernel<<<1, 256, 0, stream>>>(
            gsum1 + l * 256, gsq1 + l * 256,
            g1 + (size_t)l * D2, bt1 + (size_t)l * D2, scale1, shift1, D2);

        dim3 grid2((N_NODES + 127) / 128, 1);
        gemm2_bn_kernel<<<grid2, 256, 0, stream>>>(
            t1buf, scale1, shift1,
            W2t + (size_t)l * D * D2, b2 + (size_t)l * D, t2buf,
            gsum2 + l * 128, gsq2 + l * 128);

        bnparam_kernel<<<1, 256, 0, stream>>>(
            gsum2 + l * 128, gsq2 + l * 128,
            gbn + (size_t)l * D, bbn + (size_t)l * D,
            sc2buf + l * 128, sh2buf + l * 128, D);
    }

    bnapply2_kernel<<<(N_NODES * D / 8) / 256, 256, 0, stream>>>(
        t2buf, sc2buf + 2 * 128, sh2buf + 2 * 128, out);
}